// Round 8
// baseline (681.148 us; speedup 1.0000x reference)
//
#include <hip/hip_runtime.h>
#include <hip/hip_bf16.h>
#include <hip/hip_cooperative_groups.h>

namespace cg = cooperative_groups;

typedef __attribute__((ext_vector_type(8))) short short8;   // bf16x8 MFMA frag
typedef __attribute__((ext_vector_type(4))) float f32x4;    // fp32x4 acc

#define B_  8
#define T_  2048
#define E_  1024
#define H_  64
#define SCALE 0.03125f   // 1024^-0.5

__device__ inline unsigned short f2bf(float f) {
    unsigned int u = __builtin_bit_cast(unsigned int, f);
    unsigned int r = (u + 0x7FFFu + ((u >> 16) & 1u)) >> 16;   // RNE
    return (unsigned short)r;
}
__device__ inline unsigned int packbf(float lo, float hi) {
    return (unsigned int)f2bf(lo) | ((unsigned int)f2bf(hi) << 16);
}
__device__ inline void glds16(const void* g, void* l) {
    __builtin_amdgcn_global_load_lds((const __attribute__((address_space(1))) void*)g,
                                     (__attribute__((address_space(3))) void*)l, 16, 0, 0);
}

// ===================== fused cooperative kernel =====================
// grid 1024 x 256. LDS union 37888B -> 4 blocks/CU.
// P0: zero out + prep W | P1: qkv gemm (blocks 0..511, BK=32) | P2: col sums | P3: attn
__global__ __launch_bounds__(256, 4) void fused_all(const float* __restrict__ x,
                                                    const float* __restrict__ Wq,
                                                    const float* __restrict__ Wk,
                                                    const float* __restrict__ Wv,
                                                    unsigned short* __restrict__ Wt,
                                                    unsigned short* __restrict__ qb,
                                                    unsigned short* __restrict__ kb,
                                                    unsigned short* __restrict__ vt,
                                                    float* __restrict__ colR,
                                                    float* __restrict__ out) {
    __shared__ __align__(16) char smem[37888];
    cg::grid_group gg = cg::this_grid();
    int tid = threadIdx.x, lane = tid & 63, w = tid >> 6;
    int l15 = lane & 15, lg = lane >> 4;
    int bid = blockIdx.x;

    // ---------------- P0: zero d_out (1 float4/thread) + prep W (blocks 0..47) ------
    {
        uint4 z = (uint4){0u, 0u, 0u, 0u};
        *(uint4*)(out + ((long)bid * 256 + tid) * 4) = z;      // 1024*256*16B = 4MB exact
        if (bid < 48) {
            float (*ls)[65] = (float(*)[65])smem;              // 16640B
            int wsel = bid >> 4, kt = bid & 15;
            const float* W = (wsel == 0) ? Wq : (wsel == 1) ? Wk : Wv;
            int kr = tid >> 2, c4 = (tid & 3) * 16;
            const float* src = W + (long)(kt * 64 + kr) * H_ + c4;
            #pragma unroll
            for (int i = 0; i < 4; ++i) {
                float4 v = *(const float4*)(src + 4 * i);
                ls[kr][c4 + 4 * i + 0] = v.x; ls[kr][c4 + 4 * i + 1] = v.y;
                ls[kr][c4 + 4 * i + 2] = v.z; ls[kr][c4 + 4 * i + 3] = v.w;
            }
            __syncthreads();
            int c = tid >> 2, kk = (tid & 3) * 16;
            unsigned short* dst = Wt + (long)(wsel * 64 + c) * E_ + kt * 64 + kk;
            uint4 o1, o2;
            o1.x = packbf(ls[kk + 0][c], ls[kk + 1][c]);  o1.y = packbf(ls[kk + 2][c], ls[kk + 3][c]);
            o1.z = packbf(ls[kk + 4][c], ls[kk + 5][c]);  o1.w = packbf(ls[kk + 6][c], ls[kk + 7][c]);
            o2.x = packbf(ls[kk + 8][c], ls[kk + 9][c]);  o2.y = packbf(ls[kk + 10][c], ls[kk + 11][c]);
            o2.z = packbf(ls[kk + 12][c], ls[kk + 13][c]);o2.w = packbf(ls[kk + 14][c], ls[kk + 15][c]);
            *(uint4*)dst = o1;
            *(uint4*)(dst + 8) = o2;
        }
    }
    __threadfence();
    gg.sync();

    // ---------------- P1: QKV GEMM (blocks 0..511; 32 rows, BK=32, counted vmcnt) ---
    if (bid < 512) {
        unsigned short* wlds = (unsigned short*)smem;            // [2][192*32] = 24576B
        unsigned short* xlds = (unsigned short*)(smem + 24576);  // [2][32*40]  =  5120B
        int wr = w & 1, wc = w >> 1;
        int r0 = bid * 32;
        int b = r0 >> 11, tb = r0 & 2047;

        // W staging: wave w stages Wt-rows 48w..48w+47 in 3 glds (16 rows x 64B each).
        // LDS chunk slot s holds global chunk s ^ ((row>>1)&3)  -> 2-way-max on read.
        int r16 = lane >> 2, s4 = lane & 3;
        int g4 = s4 ^ ((r16 >> 1) & 3);
        const unsigned short* wg = Wt + (long)(48 * w + r16) * E_ + g4 * 8;
        // x staging: thread -> row xr, 4 floats at xc
        int xr = tid >> 3, xcf = (tid & 7) * 4;
        const float* xg = x + (long)(r0 + xr) * E_ + xcf;

        f32x4 acc[6];
        #pragma unroll
        for (int i = 0; i < 6; ++i) acc[i] = (f32x4){0.f, 0.f, 0.f, 0.f};

        // prologue: step 0 -> buf 0
        {
            float4 xa = *(const float4*)xg;
            #pragma unroll
            for (int j = 0; j < 3; ++j)
                glds16(wg + (long)(16 * j) * E_, wlds + (48 * w + 16 * j) * 32);
            uint2 ua; ua.x = packbf(xa.x, xa.y); ua.y = packbf(xa.z, xa.w);
            *(uint2*)&xlds[xr * 40 + xcf] = ua;
        }

        for (int ks = 0; ks < 32; ++ks) {
            int cur = ks & 1;
            __builtin_amdgcn_s_barrier();          // b1
            __builtin_amdgcn_sched_barrier(0);
            float4 xa;
            if (ks < 31) {
                int k0 = (ks + 1) * 32;
                xa = *(const float4*)(xg + k0);    // 1 vmem
                unsigned short* wd = wlds + (cur ^ 1) * 6144;
                #pragma unroll
                for (int j = 0; j < 3; ++j)        // 3 vmem
                    glds16(wg + (long)(16 * j) * E_ + k0, wd + (48 * w + 16 * j) * 32);
                asm volatile("s_waitcnt vmcnt(4) lgkmcnt(0)" ::: "memory");
            } else {
                asm volatile("s_waitcnt vmcnt(0) lgkmcnt(0)" ::: "memory");
            }
            __builtin_amdgcn_sched_barrier(0);
            __builtin_amdgcn_s_barrier();          // b2: buf cur ready
            __builtin_amdgcn_sched_barrier(0);

            const unsigned short* wb = wlds + cur * 6144;
            const unsigned short* xsb = xlds + cur * 1280;
            short8 a = *(const short8*)&xsb[(16 * wr + l15) * 40 + lg * 8];
            #pragma unroll
            for (int ct = 0; ct < 6; ++ct) {
                int c = 96 * wc + 16 * ct + l15;
                int sp = lg ^ ((c >> 1) & 3);
                short8 bf = *(const short8*)&wb[c * 32 + sp * 8];
                acc[ct] = __builtin_amdgcn_mfma_f32_16x16x32_bf16(a, bf, acc[ct], 0, 0, 0);
            }
            if (ks < 31) {
                uint2 ua; ua.x = packbf(xa.x, xa.y); ua.y = packbf(xa.z, xa.w);
                *(uint2*)&xlds[(cur ^ 1) * 1280 + xr * 40 + xcf] = ua;
            }
        }

        // q/k epilogue
        #pragma unroll
        for (int ct = 0; ct < 6; ++ct) {
            int col = 96 * wc + 16 * ct + l15;
            if (col < 128) {
                unsigned short* dst = (col < 64) ? qb : kb;
                int n = col & 63;
                #pragma unroll
                for (int r = 0; r < 4; ++r) {
                    int t = tb + 16 * wr + lg * 4 + r;
                    dst[((long)b * T_ + t) * H_ + n] = f2bf(acc[ct][r]);
                }
            }
        }
        // v epilogue via LDS transpose (vbuf = bytes 0..8704, last compute read buf1)
        float* vbuf = (float*)smem;                // [32][68]
        if (wc == 1) {
            #pragma unroll
            for (int ct = 2; ct < 6; ++ct) {
                int h = 16 * (ct - 2) + l15;
                #pragma unroll
                for (int r = 0; r < 4; ++r)
                    vbuf[(16 * wr + lg * 4 + r) * 68 + h] = acc[ct][r];
            }
        }
        __syncthreads();
        {
            int h = tid >> 2, tc = (tid & 3) * 8;
            uint4 o;
            o.x = packbf(vbuf[(tc + 0) * 68 + h], vbuf[(tc + 1) * 68 + h]);
            o.y = packbf(vbuf[(tc + 2) * 68 + h], vbuf[(tc + 3) * 68 + h]);
            o.z = packbf(vbuf[(tc + 4) * 68 + h], vbuf[(tc + 5) * 68 + h]);
            o.w = packbf(vbuf[(tc + 6) * 68 + h], vbuf[(tc + 7) * 68 + h]);
            *(uint4*)&vt[((long)b * H_ + h) * T_ + tb + tc] = o;
        }
    }
    __threadfence();
    gg.sync();

    // ---------------- P2: per-key-column sum of exp(score) over t>=s (1:1) ----------
    {
        float* lD = (float*)smem;                  // [4][16]
        int b = bid >> 7, c16 = bid & 127;
        int sbase = c16 * 16;

        const unsigned short* kp = kb + ((long)b * T_ + sbase + l15) * H_;
        short8 bk0 = *(const short8*)(kp + lg * 8);
        short8 bk1 = *(const short8*)(kp + 32 + lg * 8);

        float d1 = 0.f, d2 = 0.f;
        const unsigned short* qbase = qb + (long)b * T_ * H_;

        for (int t0 = sbase + 16 * w; t0 < T_; t0 += 128) {
            int t0b = t0 + 64;
            bool has2 = (t0b < T_);
            int t0c = has2 ? t0b : t0;
            const unsigned short* qp1 = qbase + (long)(t0 + l15) * H_ + lg * 8;
            const unsigned short* qp2 = qbase + (long)(t0c + l15) * H_ + lg * 8;
            short8 a0 = *(const short8*)qp1;
            short8 a1 = *(const short8*)(qp1 + 32);
            short8 c0 = *(const short8*)qp2;
            short8 c1 = *(const short8*)(qp2 + 32);

            f32x4 acc1 = (f32x4){0.f, 0.f, 0.f, 0.f};
            acc1 = __builtin_amdgcn_mfma_f32_16x16x32_bf16(a0, bk0, acc1, 0, 0, 0);
            acc1 = __builtin_amdgcn_mfma_f32_16x16x32_bf16(a1, bk1, acc1, 0, 0, 0);
            f32x4 acc2 = (f32x4){0.f, 0.f, 0.f, 0.f};
            acc2 = __builtin_amdgcn_mfma_f32_16x16x32_bf16(c0, bk0, acc2, 0, 0, 0);
            acc2 = __builtin_amdgcn_mfma_f32_16x16x32_bf16(c1, bk1, acc2, 0, 0, 0);

            #pragma unroll
            for (int r = 0; r < 4; ++r) {
                float e = __expf(acc1[r] * SCALE);
                if (t0 == sbase && (lg * 4 + r) < l15) e = 0.f;   // causal mask (diag tile)
                d1 += e;
            }
            if (has2) {
                #pragma unroll
                for (int r = 0; r < 4; ++r)
                    d2 += __expf(acc2[r] * SCALE);
            }
        }
        float d = d1 + d2;
        d += __shfl_xor(d, 16, 64);
        d += __shfl_xor(d, 32, 64);
        __syncthreads();                            // smem reuse guard (vbuf -> lD)
        if (lane < 16) lD[w * 16 + lane] = d;
        __syncthreads();
        if (tid < 16) {
            float df = lD[tid] + lD[16 + tid] + lD[32 + tid] + lD[48 + tid];
            colR[b * T_ + sbase + tid] = 1.0f / df;
        }
    }
    __threadfence();
    gg.sync();

    // ---------------- P3: attention output (1:1; counted vmcnt; atomic-add out) -----
    {
        unsigned short* kv = (unsigned short*)smem;           // [2][8192] = 32768B
        unsigned short* pbuf = (unsigned short*)(smem + 32768); // [4][640] = 5120B
        int qw = w & 1, sw = w >> 1;
        int p = bid & 1;
        int b = (bid >> 1) & 7;
        int j = 63 - (bid >> 4);
        int t0 = j * 32;

        const unsigned short* kbase = kb + (long)b * T_ * H_;
        const unsigned short* vbase = vt + (long)b * H_ * T_;
        const float* cR = colR + b * T_;

        const unsigned short* qp = qb + ((long)b * T_ + t0 + qw * 16 + l15) * H_ + lg * 8;
        short8 qa0 = *(const short8*)qp;
        short8 qa1 = *(const short8*)(qp + 32);

        int l8 = lane >> 3, s8 = lane & 7;
        int swz8 = (s8 ^ l8) * 8;
        const unsigned short* kg = kbase + (long)(w * 16 + l8) * H_ + swz8;
        const unsigned short* vg = vbase + (long)(w * 16 + l8) * T_ + swz8;
        unsigned short* kd0 = &kv[w * 16 * 64];
        unsigned short* vd0 = &kv[4096 + w * 16 * 64];
        unsigned short* kd1 = &kv[8192 + w * 16 * 64];
        unsigned short* vd1 = &kv[8192 + 4096 + w * 16 * 64];

        f32x4 o[4];
        #pragma unroll
        for (int i = 0; i < 4; ++i) o[i] = (f32x4){0.f, 0.f, 0.f, 0.f};
        unsigned short* myp = pbuf + w * 640;

        int nstt = j / 2 + 1;
        __syncthreads();                            // smem reuse guard (lD -> kv)

        if (p < nstt) {
            int s0 = p * 64;
            glds16(kg + (long)s0 * H_, kd0);  glds16(kg + (long)s0 * H_ + 8 * H_, kd0 + 8 * 64);
            glds16(vg + s0, vd0);             glds16(vg + s0 + 8 * T_, vd0 + 8 * 64);
        }

        int cnt = 0;
        for (int si = p; si < nstt; si += 2, ++cnt) {
            int cur = cnt & 1;
            __builtin_amdgcn_s_barrier();
            __builtin_amdgcn_sched_barrier(0);
            if (si + 2 < nstt) {
                int sn = (si + 2) * 64;
                unsigned short* kd = cur ? kd0 : kd1;
                unsigned short* vd = cur ? vd0 : vd1;
                glds16(kg + (long)sn * H_, kd);
                glds16(kg + (long)sn * H_ + 8 * H_, kd + 8 * 64);
                glds16(vg + sn, vd);
                glds16(vg + sn + 8 * T_, vd + 8 * 64);
                asm volatile("s_waitcnt vmcnt(4)" ::: "memory");
            } else {
                asm volatile("s_waitcnt vmcnt(0)" ::: "memory");
            }
            __builtin_amdgcn_sched_barrier(0);
            __builtin_amdgcn_s_barrier();
            __builtin_amdgcn_sched_barrier(0);

            int s0 = si * 64;
            const unsigned short* kt = &kv[cur * 8192];
            const unsigned short* vtl = &kv[cur * 8192 + 4096];

            #pragma unroll
            for (int ct = 0; ct < 2; ++ct) {
                int row = sw * 32 + ct * 16 + l15;
                short8 k0 = *(const short8*)&kt[row * 64 + ((0 + lg) ^ (row & 7)) * 8];
                short8 k1 = *(const short8*)&kt[row * 64 + ((4 + lg) ^ (row & 7)) * 8];
                f32x4 acc = (f32x4){0.f, 0.f, 0.f, 0.f};
                acc = __builtin_amdgcn_mfma_f32_16x16x32_bf16(qa0, k0, acc, 0, 0, 0);
                acc = __builtin_amdgcn_mfma_f32_16x16x32_bf16(qa1, k1, acc, 0, 0, 0);
                int s = s0 + row;
                float rr = cR[s];
                #pragma unroll
                for (int r = 0; r < 4; ++r) {
                    int t = t0 + qw * 16 + lg * 4 + r;
                    float pv = __expf(acc[r] * SCALE) * rr;
                    if (s > t) pv = 0.f;
                    myp[(lg * 4 + r) * 40 + ct * 16 + l15] = f2bf(pv);
                }
            }
            short8 pa = *(const short8*)&myp[l15 * 40 + lg * 8];
            #pragma unroll
            for (int ht = 0; ht < 4; ++ht) {
                int vrow = ht * 16 + l15;
                short8 vf = *(const short8*)&vtl[vrow * 64 + ((sw * 4 + lg) ^ (vrow & 7)) * 8];
                o[ht] = __builtin_amdgcn_mfma_f32_16x16x32_bf16(pa, vf, o[ht], 0, 0, 0);
            }
        }

        __syncthreads();
        float* rbuf = (float*)smem;                 // [32][68]
        if (sw == 1) {
            #pragma unroll
            for (int ht = 0; ht < 4; ++ht)
                #pragma unroll
                for (int r = 0; r < 4; ++r)
                    rbuf[(qw * 16 + lg * 4 + r) * 68 + ht * 16 + l15] = o[ht][r];
        }
        __syncthreads();
        if (sw == 0) {
            float* ob = out + ((long)b * T_ + t0 + qw * 16) * H_;
            #pragma unroll
            for (int ht = 0; ht < 4; ++ht)
                #pragma unroll
                for (int r = 0; r < 4; ++r) {
                    int rr_ = lg * 4 + r, cc = ht * 16 + l15;
                    unsafeAtomicAdd(&ob[(long)rr_ * H_ + cc],
                                    o[ht][r] + rbuf[(qw * 16 + rr_) * 68 + cc]);
                }
        }
    }
}

// ===================== fallback kernels (R7 versions) =====================
__global__ __launch_bounds__(256) void zero_prep(float* __restrict__ out,
                                                 const float* __restrict__ Wq,
                                                 const float* __restrict__ Wk,
                                                 const float* __restrict__ Wv,
                                                 unsigned short* __restrict__ Wt) {
    __shared__ float ls[64][65];
    if (blockIdx.x >= 48) {
        long bi = blockIdx.x - 48;
        uint4 z = (uint4){0u, 0u, 0u, 0u};
        *(uint4*)(out + (bi * 256 + threadIdx.x) * 4) = z;
        return;
    }
    int tid = threadIdx.x;
    int wsel = blockIdx.x >> 4, kt = blockIdx.x & 15;
    const float* W = (wsel == 0) ? Wq : (wsel == 1) ? Wk : Wv;
    int kr = tid >> 2, c4 = (tid & 3) * 16;
    const float* src = W + (long)(kt * 64 + kr) * H_ + c4;
    #pragma unroll
    for (int i = 0; i < 4; ++i) {
        float4 v = *(const float4*)(src + 4 * i);
        ls[kr][c4 + 4 * i + 0] = v.x; ls[kr][c4 + 4 * i + 1] = v.y;
        ls[kr][c4 + 4 * i + 2] = v.z; ls[kr][c4 + 4 * i + 3] = v.w;
    }
    __syncthreads();
    int c = tid >> 2, kk = (tid & 3) * 16;
    unsigned short* dst = Wt + (long)(wsel * 64 + c) * E_ + kt * 64 + kk;
    uint4 o1, o2;
    o1.x = packbf(ls[kk + 0][c], ls[kk + 1][c]);  o1.y = packbf(ls[kk + 2][c], ls[kk + 3][c]);
    o1.z = packbf(ls[kk + 4][c], ls[kk + 5][c]);  o1.w = packbf(ls[kk + 6][c], ls[kk + 7][c]);
    o2.x = packbf(ls[kk + 8][c], ls[kk + 9][c]);  o2.y = packbf(ls[kk + 10][c], ls[kk + 11][c]);
    o2.z = packbf(ls[kk + 12][c], ls[kk + 13][c]);o2.w = packbf(ls[kk + 14][c], ls[kk + 15][c]);
    *(uint4*)dst = o1;
    *(uint4*)(dst + 8) = o2;
}

__global__ __launch_bounds__(256) void qkv_gemm(const float* __restrict__ x,
                                                const unsigned short* __restrict__ Wt,
                                                unsigned short* __restrict__ qb,
                                                unsigned short* __restrict__ kb,
                                                unsigned short* __restrict__ vt) {
    __shared__ unsigned short wlds[2][192 * 64];
    __shared__ unsigned short xlds[2][32 * 72];

    int tid = threadIdx.x, lane = tid & 63, w = tid >> 6;
    int l15 = lane & 15, lg = lane >> 4;
    int wr = w & 1, wc = w >> 1;
    int r0 = blockIdx.x * 32;
    int b = r0 >> 11, tb = r0 & 2047;

    int l8 = lane >> 3, s8 = lane & 7;
    int swz = s8 ^ l8;
    const unsigned short* wg = Wt + (long)(48 * w + l8) * E_ + swz * 8;
    unsigned short* wl0 = &wlds[0][(48 * w) * 64];
    unsigned short* wl1 = &wlds[1][(48 * w) * 64];

    int xr = tid >> 3, xc = tid & 7;
    const float* xg = x + (long)(r0 + xr) * E_ + xc * 8;

    f32x4 acc[6];
    #pragma unroll
    for (int i = 0; i < 6; ++i) acc[i] = (f32x4){0.f, 0.f, 0.f, 0.f};

    {
        float4 xa = *(const float4*)xg;
        float4 xb = *(const float4*)(xg + 4);
        #pragma unroll
        for (int j = 0; j < 6; ++j)
            glds16(wg + (long)(8 * j) * E_, wl0 + (8 * j) * 64);
        uint4 ua;
        ua.x = packbf(xa.x, xa.y); ua.y = packbf(xa.z, xa.w);
        ua.z = packbf(xb.x, xb.y); ua.w = packbf(xb.z, xb.w);
        *(uint4*)((char*)&xlds[0][0] + xr * 144 + xc * 16) = ua;
    }

    for (int ks = 0; ks < 16; ++ks) {
        int cur = ks & 1;
        __builtin_amdgcn_s_barrier();
        __builtin_amdgcn_sched_barrier(0);
        float4 xa, xb;
        if (ks < 15) {
            int kp = (ks + 1) * 64;
            xa = *(const float4*)(xg + kp);
            xb = *(const float4*)(xg + kp + 4);
            unsigned short* wldst = cur ? wl0 : wl1;
            #pragma unroll
            for (int j = 0; j < 6; ++j)
                glds16(wg + (long)(8 * j) * E_ + kp, wldst + (8 * j) * 64);
            asm volatile("s_waitcnt vmcnt(8) lgkmcnt(0)" ::: "memory");
        } else {
            asm volatile("s_waitcnt vmcnt(0) lgkmcnt(0)" ::: "memory");
        }
        __builtin_amdgcn_sched_barrier(0);
        __builtin_amdgcn_s_barrier();
        __builtin_amdgcn_sched_barrier(0);

        const char* wb = (const char*)&wlds[cur][0];
        const char* xsb = (const char*)&xlds[cur][0];
        #pragma unroll
        for (int kk2 = 0; kk2 < 2; ++kk2) {
            short8 a = *(const short8*)(xsb + (16 * wr + l15) * 144 + kk2 * 64 + lg * 16);
            #pragma unroll
            for (int ct = 0; ct < 6; ++ct) {
                int c = 96 * wc + 16 * ct + l15;
                int sp = (kk2 * 4 + lg) ^ (c & 7);
                short8 bf = *(const short8*)(wb + c * 128 + sp * 16);
                acc[ct] = __builtin_amdgcn_mfma_f32_16x16x32_bf16(a, bf, acc[ct], 0, 0, 0);
            }
        }
        if (ks < 15) {
            uint4 ua;
            ua.x = packbf(xa.x, xa.y); ua.y = packbf(xa.z, xa.w);
            ua.z = packbf(xb.x, xb.y); ua.w = packbf(xb.z, xb.w);
            *(uint4*)((char*)&xlds[cur ^ 1][0] + xr * 144 + xc * 16) = ua;
        }
    }

    #pragma unroll
    for (int ct = 0; ct < 6; ++ct) {
        int col = 96 * wc + 16 * ct + l15;
        if (col < 128) {
            unsigned short* dst = (col < 64) ? qb : kb;
            int n = col & 63;
            #pragma unroll
            for (int r = 0; r < 4; ++r) {
                int t = tb + 16 * wr + lg * 4 + r;
                dst[((long)b * T_ + t) * H_ + n] = f2bf(acc[ct][r]);
            }
        }
    }
    float* vbuf = (float*)&wlds[0][0];
    if (wc == 1) {
        #pragma unroll
        for (int ct = 2; ct < 6; ++ct) {
            int h = 16 * (ct - 2) + l15;
            #pragma unroll
            for (int r = 0; r < 4; ++r)
                vbuf[(16 * wr + lg * 4 + r) * 68 + h] = acc[ct][r];
        }
    }
    __syncthreads();
    {
        int h = tid >> 2, tc = (tid & 3) * 8;
        uint4 o;
        o.x = packbf(vbuf[(tc + 0) * 68 + h], vbuf[(tc + 1) * 68 + h]);
        o.y = packbf(vbuf[(tc + 2) * 68 + h], vbuf[(tc + 3) * 68 + h]);
        o.z = packbf(vbuf[(tc + 4) * 68 + h], vbuf[(tc + 5) * 68 + h]);
        o.w = packbf(vbuf[(tc + 6) * 68 + h], vbuf[(tc + 7) * 68 + h]);
        *(uint4*)&vt[((long)b * H_ + h) * T_ + tb + tc] = o;
    }
}

__global__ __launch_bounds__(256) void col_stats(const unsigned short* __restrict__ qb,
                                                 const unsigned short* __restrict__ kb,
                                                 float* __restrict__ colR) {
    __shared__ float lD[4][16];
    int tid = threadIdx.x, lane = tid & 63, w = tid >> 6;
    int b = blockIdx.x >> 7, c16 = blockIdx.x & 127;
    int sbase = c16 * 16;
    int l15 = lane & 15, lg = lane >> 4;

    const unsigned short* kp = kb + ((long)b * T_ + sbase + l15) * H_;
    short8 bk0 = *(const short8*)(kp + lg * 8);
    short8 bk1 = *(const short8*)(kp + 32 + lg * 8);

    float d1 = 0.f, d2 = 0.f;
    const unsigned short* qbase = qb + (long)b * T_ * H_;

    for (int t0 = sbase + 16 * w; t0 < T_; t0 += 128) {
        int t0b = t0 + 64;
        bool has2 = (t0b < T_);
        int t0c = has2 ? t0b : t0;
        const unsigned short* qp1 = qbase + (long)(t0 + l15) * H_ + lg * 8;
        const unsigned short* qp2 = qbase + (long)(t0c + l15) * H_ + lg * 8;
        short8 a0 = *(const short8*)qp1;
        short8 a1 = *(const short8*)(qp1 + 32);
        short8 c0 = *(const short8*)qp2;
        short8 c1 = *(const short8*)(qp2 + 32);

        f32x4 acc1 = (f32x4){0.f, 0.f, 0.f, 0.f};
        acc1 = __builtin_amdgcn_mfma_f32_16x16x32_bf16(a0, bk0, acc1, 0, 0, 0);
        acc1 = __builtin_amdgcn_mfma_f32_16x16x32_bf16(a1, bk1, acc1, 0, 0, 0);
        f32x4 acc2 = (f32x4){0.f, 0.f, 0.f, 0.f};
        acc2 = __builtin_amdgcn_mfma_f32_16x16x32_bf16(c0, bk0, acc2, 0, 0, 0);
        acc2 = __builtin_amdgcn_mfma_f32_16x16x32_bf16(c1, bk1, acc2, 0, 0, 0);

        #pragma unroll
        for (int r = 0; r < 4; ++r) {
            float e = __expf(acc1[r] * SCALE);
            if (t0 == sbase && (lg * 4 + r) < l15) e = 0.f;
            d1 += e;
        }
        if (has2) {
            #pragma unroll
            for (int r = 0; r < 4; ++r)
                d2 += __expf(acc2[r] * SCALE);
        }
    }
    float d = d1 + d2;
    d += __shfl_xor(d, 16, 64);
    d += __shfl_xor(d, 32, 64);
    if (lane < 16) lD[w][lane] = d;
    __syncthreads();
    if (tid < 16) {
        float df = lD[0][tid] + lD[1][tid] + lD[2][tid] + lD[3][tid];
        colR[b * T_ + sbase + tid] = 1.0f / df;
    }
}

__global__ __launch_bounds__(256, 4) void attn_out(const unsigned short* __restrict__ qb,
                                                   const unsigned short* __restrict__ kb,
                                                   const unsigned short* __restrict__ vt,
                                                   const float* __restrict__ colR,
                                                   float* __restrict__ out) {
    __shared__ unsigned short kv[2][8192];
    __shared__ unsigned short pbuf[4][16 * 40];

    int tid = threadIdx.x, lane = tid & 63, w = tid >> 6;
    int qw = w & 1, sw = w >> 1;
    int l15 = lane & 15, lg = lane >> 4;
    int idx = blockIdx.x;
    int p = idx & 1;
    int b = (idx >> 1) & 7;
    int j = 63 - (idx >> 4);
    int t0 = j * 32;

    const unsigned short* kbase = kb + (long)b * T_ * H_;
    const unsigned short* vbase = vt + (long)b * H_ * T_;
    const float* cR = colR + b * T_;

    const unsigned short* qp = qb + ((long)b * T_ + t0 + qw * 16 + l15) * H_ + lg * 8;
    short8 qa0 = *(const short8*)qp;
    short8 qa1 = *(const short8*)(qp + 32);

    int l8 = lane >> 3, s8 = lane & 7;
    int swz8 = (s8 ^ l8) * 8;
    const unsigned short* kg = kbase + (long)(w * 16 + l8) * H_ + swz8;
    const unsigned short* vg = vbase + (long)(w * 16 + l8) * T_ + swz8;
    unsigned short* kd0 = &kv[0][w * 16 * 64];
    unsigned short* vd0 = &kv[0][4096 + w * 16 * 64];
    unsigned short* kd1 = &kv[1][w * 16 * 64];
    unsigned short* vd1 = &kv[1][4096 + w * 16 * 64];

    f32x4 o[4];
    #pragma unroll
    for (int i = 0; i < 4; ++i) o[i] = (f32x4){0.f, 0.f, 0.f, 0.f};
    unsigned short* myp = pbuf[w];

    int nstt = j / 2 + 1;

    if (p < nstt) {
        int s0 = p * 64;
        glds16(kg + (long)s0 * H_, kd0);  glds16(kg + (long)s0 * H_ + 8 * H_, kd0 + 8 * 64);
        glds16(vg + s0, vd0);             glds16(vg + s0 + 8 * T_, vd0 + 8 * 64);
    }

    int cnt = 0;
    for (int si = p; si < nstt; si += 2, ++cnt) {
        int cur = cnt & 1;
        __builtin_amdgcn_s_barrier();
        __builtin_amdgcn_sched_barrier(0);
        if (si + 2 < nstt) {
            int sn = (si + 2) * 64;
            unsigned short* kd = cur ? kd0 : kd1;
            unsigned short* vd = cur ? vd0 : vd1;
            glds16(kg + (long)sn * H_, kd);
            glds16(kg + (long)sn * H_ + 8 * H_, kd + 8 * 64);
            glds16(vg + sn, vd);
            glds16(vg + sn + 8 * T_, vd + 8 * 64);
            asm volatile("s_waitcnt vmcnt(4)" ::: "memory");
        } else {
            asm volatile("s_waitcnt vmcnt(0)" ::: "memory");
        }
        __builtin_amdgcn_sched_barrier(0);
        __builtin_amdgcn_s_barrier();
        __builtin_amdgcn_sched_barrier(0);

        int s0 = si * 64;
        const unsigned short* kt = &kv[cur][0];
        const unsigned short* vtl = &kv[cur][4096];

        #pragma unroll
        for (int ct = 0; ct < 2; ++ct) {
            int row = sw * 32 + ct * 16 + l15;
            short8 k0 = *(const short8*)&kt[row * 64 + ((0 + lg) ^ (row & 7)) * 8];
            short8 k1 = *(const short8*)&kt[row * 64 + ((4 + lg) ^ (row & 7)) * 8];
            f32x4 acc = (f32x4){0.f, 0.f, 0.f, 0.f};
            acc = __builtin_amdgcn_mfma_f32_16x16x32_bf16(qa0, k0, acc, 0, 0, 0);
            acc = __builtin_amdgcn_mfma_f32_16x16x32_bf16(qa1, k1, acc, 0, 0, 0);
            int s = s0 + row;
            float rr = cR[s];
            #pragma unroll
            for (int r = 0; r < 4; ++r) {
                int t = t0 + qw * 16 + lg * 4 + r;
                float pv = __expf(acc[r] * SCALE) * rr;
                if (s > t) pv = 0.f;
                myp[(lg * 4 + r) * 40 + ct * 16 + l15] = f2bf(pv);
            }
        }
        short8 pa = *(const short8*)&myp[l15 * 40 + lg * 8];
        #pragma unroll
        for (int ht = 0; ht < 4; ++ht) {
            int vrow = ht * 16 + l15;
            short8 vf = *(const short8*)&vtl[vrow * 64 + ((sw * 4 + lg) ^ (vrow & 7)) * 8];
            o[ht] = __builtin_amdgcn_mfma_f32_16x16x32_bf16(pa, vf, o[ht], 0, 0, 0);
        }
    }

    __syncthreads();
    float* rbuf = (float*)&kv[0][0];
    if (sw == 1) {
        #pragma unroll
        for (int ht = 0; ht < 4; ++ht)
            #pragma unroll
            for (int r = 0; r < 4; ++r)
                rbuf[(qw * 16 + lg * 4 + r) * 68 + ht * 16 + l15] = o[ht][r];
    }
    __syncthreads();
    if (sw == 0) {
        float* ob = out + ((long)b * T_ + t0 + qw * 16) * H_;
        #pragma unroll
        for (int ht = 0; ht < 4; ++ht)
            #pragma unroll
            for (int r = 0; r < 4; ++r) {
                int rr_ = lg * 4 + r, cc = ht * 16 + l15;
                unsafeAtomicAdd(&ob[(long)rr_ * H_ + cc],
                                o[ht][r] + rbuf[(qw * 16 + rr_) * 68 + cc]);
            }
    }
}

extern "C" void kernel_launch(void* const* d_in, const int* in_sizes, int n_in,
                              void* d_out, int out_size, void* d_ws, size_t ws_size,
                              hipStream_t stream) {
    const float* x  = (const float*)d_in[0];
    const float* Wk = (const float*)d_in[1];
    const float* Wq = (const float*)d_in[2];
    const float* Wv = (const float*)d_in[3];
    float* out = (float*)d_out;

    char* ws = (char*)d_ws;
    unsigned short* Wt = (unsigned short*)ws;                                  // 393216 B
    unsigned short* qb = (unsigned short*)(ws + 393216);                       // 2 MB
    unsigned short* kb = (unsigned short*)(ws + 393216 + 2097152);             // 2 MB
    unsigned short* vt = (unsigned short*)(ws + 393216 + 2 * 2097152);         // 2 MB
    float* colR = (float*)(ws + 393216 + 3 * 2097152);                         // 64 KB

    void* kargs[] = {(void*)&x, (void*)&Wq, (void*)&Wk, (void*)&Wv,
                     (void*)&Wt, (void*)&qb, (void*)&kb, (void*)&vt,
                     (void*)&colR, (void*)&out};
    hipError_t e = hipLaunchCooperativeKernel((const void*)fused_all,
                                              dim3(1024), dim3(256), kargs, 0, stream);
    if (e != hipSuccess) {
        // fallback: R7 multi-kernel path
        zero_prep<<<1072, 256, 0, stream>>>(out, Wq, Wk, Wv, Wt);
        qkv_gemm <<<512,  256, 0, stream>>>(x, Wt, qb, kb, vt);
        col_stats<<<1024, 256, 0, stream>>>(qb, kb, colR);
        attn_out <<<1024, 256, 0, stream>>>(qb, kb, vt, colR, out);
    }
}

// Round 9
// 87.730 us; speedup vs baseline: 7.7641x; 7.7641x over previous
//
#include <hip/hip_runtime.h>
#include <hip/hip_bf16.h>

typedef __attribute__((ext_vector_type(8))) short short8;   // bf16x8 MFMA frag
typedef __attribute__((ext_vector_type(4))) float f32x4;    // fp32x4 acc

#define B_  8
#define T_  2048
#define E_  1024
#define H_  64
#define SCALE 0.03125f   // 1024^-0.5

__device__ inline unsigned short f2bf(float f) {
    unsigned int u = __builtin_bit_cast(unsigned int, f);
    unsigned int r = (u + 0x7FFFu + ((u >> 16) & 1u)) >> 16;   // RNE
    return (unsigned short)r;
}
__device__ inline unsigned int packbf(float lo, float hi) {
    return (unsigned int)f2bf(lo) | ((unsigned int)f2bf(hi) << 16);
}
__device__ inline void glds16(const void* g, void* l) {
    __builtin_amdgcn_global_load_lds((const __attribute__((address_space(1))) void*)g,
                                     (__attribute__((address_space(3))) void*)l, 16, 0, 0);
}

// ------------- kernel 0: fused {zero d_out (4MB)} + {W fp32 -> Wt bf16 transposed} ---
__global__ __launch_bounds__(256) void zero_prep(float* __restrict__ out,
                                                 const float* __restrict__ Wq,
                                                 const float* __restrict__ Wk,
                                                 const float* __restrict__ Wv,
                                                 unsigned short* __restrict__ Wt) {
    __shared__ float ls[64][65];
    if (blockIdx.x >= 48) {                       // zero part: 1024 blocks
        long bi = blockIdx.x - 48;
        uint4 z = (uint4){0u, 0u, 0u, 0u};
        *(uint4*)(out + (bi * 256 + threadIdx.x) * 4) = z;
        return;
    }
    int tid = threadIdx.x;
    int wsel = blockIdx.x >> 4, kt = blockIdx.x & 15;
    const float* W = (wsel == 0) ? Wq : (wsel == 1) ? Wk : Wv;
    int kr = tid >> 2, c4 = (tid & 3) * 16;
    const float* src = W + (long)(kt * 64 + kr) * H_ + c4;
    #pragma unroll
    for (int i = 0; i < 4; ++i) {
        float4 v = *(const float4*)(src + 4 * i);
        ls[kr][c4 + 4 * i + 0] = v.x; ls[kr][c4 + 4 * i + 1] = v.y;
        ls[kr][c4 + 4 * i + 2] = v.z; ls[kr][c4 + 4 * i + 3] = v.w;
    }
    __syncthreads();
    int c = tid >> 2, kk = (tid & 3) * 16;
    unsigned short* dst = Wt + (long)(wsel * 64 + c) * E_ + kt * 64 + kk;
    uint4 o1, o2;
    o1.x = packbf(ls[kk + 0][c], ls[kk + 1][c]);  o1.y = packbf(ls[kk + 2][c], ls[kk + 3][c]);
    o1.z = packbf(ls[kk + 4][c], ls[kk + 5][c]);  o1.w = packbf(ls[kk + 6][c], ls[kk + 7][c]);
    o2.x = packbf(ls[kk + 8][c], ls[kk + 9][c]);  o2.y = packbf(ls[kk + 10][c], ls[kk + 11][c]);
    o2.z = packbf(ls[kk + 12][c], ls[kk + 13][c]);o2.w = packbf(ls[kk + 14][c], ls[kk + 15][c]);
    *(uint4*)dst = o1;
    *(uint4*)(dst + 8) = o2;
}

// ---------------- kernel 1: QKV GEMM  [16384,1024] @ [1024,192], BK=32 --------------
// LDS 29.7KB -> 5 blocks/CU. Counted-vmcnt pipeline (verified in R8's fused P1).
// W LDS chunk slot s holds global chunk s ^ ((row>>1)&3) (2-way-max bank aliasing).
__global__ __launch_bounds__(256, 5) void qkv_gemm(const float* __restrict__ x,
                                                   const unsigned short* __restrict__ Wt,
                                                   unsigned short* __restrict__ qb,
                                                   unsigned short* __restrict__ kb,
                                                   unsigned short* __restrict__ vt) {
    __shared__ unsigned short wlds[2][192 * 32];   // 24576 B (linear glds dest)
    __shared__ unsigned short xlds[2][32 * 40];    // 5120 B (pad 8)

    int tid = threadIdx.x, lane = tid & 63, w = tid >> 6;
    int l15 = lane & 15, lg = lane >> 4;
    int wr = w & 1, wc = w >> 1;
    int r0 = blockIdx.x * 32;
    int b = r0 >> 11, tb = r0 & 2047;

    // W staging: wave w stages Wt-rows 48w..48w+47 in 3 glds (16 rows x 64B each)
    int r16 = lane >> 2, s4 = lane & 3;
    int g4 = s4 ^ ((r16 >> 1) & 3);
    const unsigned short* wg = Wt + (long)(48 * w + r16) * E_ + g4 * 8;
    // x staging: thread -> row xr, 4 floats at xcf
    int xr = tid >> 3, xcf = (tid & 7) * 4;
    const float* xg = x + (long)(r0 + xr) * E_ + xcf;

    f32x4 acc[6];
    #pragma unroll
    for (int i = 0; i < 6; ++i) acc[i] = (f32x4){0.f, 0.f, 0.f, 0.f};

    // prologue: step 0 -> buf 0
    {
        float4 xa = *(const float4*)xg;
        #pragma unroll
        for (int j = 0; j < 3; ++j)
            glds16(wg + (long)(16 * j) * E_, &wlds[0][(48 * w + 16 * j) * 32]);
        uint2 ua; ua.x = packbf(xa.x, xa.y); ua.y = packbf(xa.z, xa.w);
        *(uint2*)&xlds[0][xr * 40 + xcf] = ua;
    }

    for (int ks = 0; ks < 32; ++ks) {
        int cur = ks & 1;
        __builtin_amdgcn_s_barrier();              // b1: all waves done with prev compute
        __builtin_amdgcn_sched_barrier(0);
        float4 xa;
        if (ks < 31) {
            int k0 = (ks + 1) * 32;
            xa = *(const float4*)(xg + k0);        // 1 vmem
            #pragma unroll
            for (int j = 0; j < 3; ++j)            // 3 vmem (glds)
                glds16(wg + (long)(16 * j) * E_ + k0, &wlds[cur ^ 1][(48 * w + 16 * j) * 32]);
            asm volatile("s_waitcnt vmcnt(4) lgkmcnt(0)" ::: "memory");
        } else {
            asm volatile("s_waitcnt vmcnt(0) lgkmcnt(0)" ::: "memory");
        }
        __builtin_amdgcn_sched_barrier(0);
        __builtin_amdgcn_s_barrier();              // b2: buf cur ready
        __builtin_amdgcn_sched_barrier(0);

        const unsigned short* wb = &wlds[cur][0];
        const unsigned short* xsb = &xlds[cur][0];
        short8 a = *(const short8*)&xsb[(16 * wr + l15) * 40 + lg * 8];
        #pragma unroll
        for (int ct = 0; ct < 6; ++ct) {
            int c = 96 * wc + 16 * ct + l15;
            int sp = lg ^ ((c >> 1) & 3);
            short8 bf = *(const short8*)&wb[c * 32 + sp * 8];
            acc[ct] = __builtin_amdgcn_mfma_f32_16x16x32_bf16(a, bf, acc[ct], 0, 0, 0);
        }
        if (ks < 31) {                             // x -> next buf (write after compute)
            uint2 ua; ua.x = packbf(xa.x, xa.y); ua.y = packbf(xa.z, xa.w);
            *(uint2*)&xlds[cur ^ 1][xr * 40 + xcf] = ua;
        }
    }

    // q/k epilogue
    #pragma unroll
    for (int ct = 0; ct < 6; ++ct) {
        int col = 96 * wc + 16 * ct + l15;
        if (col < 128) {
            unsigned short* dst = (col < 64) ? qb : kb;
            int n = col & 63;
            #pragma unroll
            for (int r = 0; r < 4; ++r) {
                int t = tb + 16 * wr + lg * 4 + r;
                dst[((long)b * T_ + t) * H_ + n] = f2bf(acc[ct][r]);
            }
        }
    }
    // v epilogue via LDS transpose (reuse wlds; last compute done)
    __syncthreads();
    float* vbuf = (float*)&wlds[0][0];             // [32][68] fp32 = 8704B
    if (wc == 1) {
        #pragma unroll
        for (int ct = 2; ct < 6; ++ct) {
            int h = 16 * (ct - 2) + l15;
            #pragma unroll
            for (int r = 0; r < 4; ++r)
                vbuf[(16 * wr + lg * 4 + r) * 68 + h] = acc[ct][r];
        }
    }
    __syncthreads();
    {
        int h = tid >> 2, tc = (tid & 3) * 8;
        uint4 o;
        o.x = packbf(vbuf[(tc + 0) * 68 + h], vbuf[(tc + 1) * 68 + h]);
        o.y = packbf(vbuf[(tc + 2) * 68 + h], vbuf[(tc + 3) * 68 + h]);
        o.z = packbf(vbuf[(tc + 4) * 68 + h], vbuf[(tc + 5) * 68 + h]);
        o.w = packbf(vbuf[(tc + 6) * 68 + h], vbuf[(tc + 7) * 68 + h]);
        *(uint4*)&vt[((long)b * H_ + h) * T_ + tb + tc] = o;
    }
}

// ---------------- kernel 2: per-key-column sum of exp(score) over t>=s ---------------
__global__ __launch_bounds__(256) void col_stats(const unsigned short* __restrict__ qb,
                                                 const unsigned short* __restrict__ kb,
                                                 float* __restrict__ colR) {
    __shared__ float lD[4][16];
    int tid = threadIdx.x, lane = tid & 63, w = tid >> 6;
    int b = blockIdx.x >> 7, c16 = blockIdx.x & 127;
    int sbase = c16 * 16;
    int l15 = lane & 15, lg = lane >> 4;

    const unsigned short* kp = kb + ((long)b * T_ + sbase + l15) * H_;
    short8 bk0 = *(const short8*)(kp + lg * 8);
    short8 bk1 = *(const short8*)(kp + 32 + lg * 8);

    float d1 = 0.f, d2 = 0.f;
    const unsigned short* qbase = qb + (long)b * T_ * H_;

    for (int t0 = sbase + 16 * w; t0 < T_; t0 += 128) {
        int t0b = t0 + 64;
        bool has2 = (t0b < T_);
        int t0c = has2 ? t0b : t0;
        const unsigned short* qp1 = qbase + (long)(t0 + l15) * H_ + lg * 8;
        const unsigned short* qp2 = qbase + (long)(t0c + l15) * H_ + lg * 8;
        short8 a0 = *(const short8*)qp1;
        short8 a1 = *(const short8*)(qp1 + 32);
        short8 c0 = *(const short8*)qp2;
        short8 c1 = *(const short8*)(qp2 + 32);

        f32x4 acc1 = (f32x4){0.f, 0.f, 0.f, 0.f};
        acc1 = __builtin_amdgcn_mfma_f32_16x16x32_bf16(a0, bk0, acc1, 0, 0, 0);
        acc1 = __builtin_amdgcn_mfma_f32_16x16x32_bf16(a1, bk1, acc1, 0, 0, 0);
        f32x4 acc2 = (f32x4){0.f, 0.f, 0.f, 0.f};
        acc2 = __builtin_amdgcn_mfma_f32_16x16x32_bf16(c0, bk0, acc2, 0, 0, 0);
        acc2 = __builtin_amdgcn_mfma_f32_16x16x32_bf16(c1, bk1, acc2, 0, 0, 0);

        #pragma unroll
        for (int r = 0; r < 4; ++r) {
            float e = __expf(acc1[r] * SCALE);
            if (t0 == sbase && (lg * 4 + r) < l15) e = 0.f;   // causal mask (diag tile)
            d1 += e;
        }
        if (has2) {
            #pragma unroll
            for (int r = 0; r < 4; ++r)
                d2 += __expf(acc2[r] * SCALE);
        }
    }
    float d = d1 + d2;
    d += __shfl_xor(d, 16, 64);
    d += __shfl_xor(d, 32, 64);
    if (lane < 16) lD[w][lane] = d;
    __syncthreads();
    if (tid < 16) {
        float df = lD[0][tid] + lD[1][tid] + lD[2][tid] + lD[3][tid];
        colR[b * T_ + sbase + tid] = 1.0f / df;
    }
}

// ---------------- kernel 3: out[t,h] = sum_{s<=t} exp(score)*R[s] * v[s,h] ----------
__global__ __launch_bounds__(256, 4) void attn_out(const unsigned short* __restrict__ qb,
                                                   const unsigned short* __restrict__ kb,
                                                   const unsigned short* __restrict__ vt,
                                                   const float* __restrict__ colR,
                                                   float* __restrict__ out) {
    __shared__ unsigned short kv[2][8192];        // [buf][ K 64x64 | V 64x64 ]  32 KB
    __shared__ unsigned short pbuf[4][16 * 40];   // per-wave P [16 q][32 s]      5 KB

    int tid = threadIdx.x, lane = tid & 63, w = tid >> 6;
    int qw = w & 1, sw = w >> 1;
    int l15 = lane & 15, lg = lane >> 4;
    int idx = blockIdx.x;
    int p = idx & 1;
    int b = (idx >> 1) & 7;
    int j = 63 - (idx >> 4);
    int t0 = j * 32;

    const unsigned short* kbase = kb + (long)b * T_ * H_;
    const unsigned short* vbase = vt + (long)b * H_ * T_;
    const float* cR = colR + b * T_;

    const unsigned short* qp = qb + ((long)b * T_ + t0 + qw * 16 + l15) * H_ + lg * 8;
    short8 qa0 = *(const short8*)qp;
    short8 qa1 = *(const short8*)(qp + 32);

    int l8 = lane >> 3, s8 = lane & 7;
    int swz8 = (s8 ^ l8) * 8;
    const unsigned short* kg = kbase + (long)(w * 16 + l8) * H_ + swz8;
    const unsigned short* vg = vbase + (long)(w * 16 + l8) * T_ + swz8;
    unsigned short* kd0 = &kv[0][w * 16 * 64];
    unsigned short* vd0 = &kv[0][4096 + w * 16 * 64];
    unsigned short* kd1 = &kv[1][w * 16 * 64];
    unsigned short* vd1 = &kv[1][4096 + w * 16 * 64];

    f32x4 o[4];
    #pragma unroll
    for (int i = 0; i < 4; ++i) o[i] = (f32x4){0.f, 0.f, 0.f, 0.f};
    unsigned short* myp = pbuf[w];

    int nstt = j / 2 + 1;

    if (p < nstt) {
        int s0 = p * 64;
        glds16(kg + (long)s0 * H_, kd0);  glds16(kg + (long)s0 * H_ + 8 * H_, kd0 + 8 * 64);
        glds16(vg + s0, vd0);             glds16(vg + s0 + 8 * T_, vd0 + 8 * 64);
    }

    int cnt = 0;
    for (int si = p; si < nstt; si += 2, ++cnt) {
        int cur = cnt & 1;
        __builtin_amdgcn_s_barrier();
        __builtin_amdgcn_sched_barrier(0);
        if (si + 2 < nstt) {
            int sn = (si + 2) * 64;
            unsigned short* kd = cur ? kd0 : kd1;
            unsigned short* vd = cur ? vd0 : vd1;
            glds16(kg + (long)sn * H_, kd);
            glds16(kg + (long)sn * H_ + 8 * H_, kd + 8 * 64);
            glds16(vg + sn, vd);
            glds16(vg + sn + 8 * T_, vd + 8 * 64);
            asm volatile("s_waitcnt vmcnt(4)" ::: "memory");
        } else {
            asm volatile("s_waitcnt vmcnt(0)" ::: "memory");
        }
        __builtin_amdgcn_sched_barrier(0);
        __builtin_amdgcn_s_barrier();
        __builtin_amdgcn_sched_barrier(0);

        int s0 = si * 64;
        const unsigned short* kt = &kv[cur][0];
        const unsigned short* vtl = &kv[cur][4096];

        #pragma unroll
        for (int ct = 0; ct < 2; ++ct) {
            int row = sw * 32 + ct * 16 + l15;
            short8 k0 = *(const short8*)&kt[row * 64 + ((0 + lg) ^ (row & 7)) * 8];
            short8 k1 = *(const short8*)&kt[row * 64 + ((4 + lg) ^ (row & 7)) * 8];
            f32x4 acc = (f32x4){0.f, 0.f, 0.f, 0.f};
            acc = __builtin_amdgcn_mfma_f32_16x16x32_bf16(qa0, k0, acc, 0, 0, 0);
            acc = __builtin_amdgcn_mfma_f32_16x16x32_bf16(qa1, k1, acc, 0, 0, 0);
            int s = s0 + row;
            float rr = cR[s];
            #pragma unroll
            for (int r = 0; r < 4; ++r) {
                int t = t0 + qw * 16 + lg * 4 + r;
                float pv = __expf(acc[r] * SCALE) * rr;
                if (s > t) pv = 0.f;
                myp[(lg * 4 + r) * 40 + ct * 16 + l15] = f2bf(pv);
            }
        }
        short8 pa = *(const short8*)&myp[l15 * 40 + lg * 8];
        #pragma unroll
        for (int ht = 0; ht < 4; ++ht) {
            int vrow = ht * 16 + l15;
            short8 vf = *(const short8*)&vtl[vrow * 64 + ((sw * 4 + lg) ^ (vrow & 7)) * 8];
            o[ht] = __builtin_amdgcn_mfma_f32_16x16x32_bf16(pa, vf, o[ht], 0, 0, 0);
        }
    }

    __syncthreads();
    float* rbuf = (float*)&kv[0][0];               // [32 q][68] f32
    if (sw == 1) {
        #pragma unroll
        for (int ht = 0; ht < 4; ++ht)
            #pragma unroll
            for (int r = 0; r < 4; ++r)
                rbuf[(qw * 16 + lg * 4 + r) * 68 + ht * 16 + l15] = o[ht][r];
    }
    __syncthreads();
    if (sw == 0) {
        float* ob = out + ((long)b * T_ + t0 + qw * 16) * H_;
        #pragma unroll
        for (int ht = 0; ht < 4; ++ht)
            #pragma unroll
            for (int r = 0; r < 4; ++r) {
                int rr_ = lg * 4 + r, cc = ht * 16 + l15;
                unsafeAtomicAdd(&ob[(long)rr_ * H_ + cc],
                                o[ht][r] + rbuf[(qw * 16 + rr_) * 68 + cc]);
            }
    }
}

extern "C" void kernel_launch(void* const* d_in, const int* in_sizes, int n_in,
                              void* d_out, int out_size, void* d_ws, size_t ws_size,
                              hipStream_t stream) {
    const float* x  = (const float*)d_in[0];
    const float* Wk = (const float*)d_in[1];
    const float* Wq = (const float*)d_in[2];
    const float* Wv = (const float*)d_in[3];
    float* out = (float*)d_out;

    char* ws = (char*)d_ws;
    unsigned short* Wt = (unsigned short*)ws;                                  // 393216 B
    unsigned short* qb = (unsigned short*)(ws + 393216);                       // 2 MB
    unsigned short* kb = (unsigned short*)(ws + 393216 + 2097152);             // 2 MB
    unsigned short* vt = (unsigned short*)(ws + 393216 + 2 * 2097152);         // 2 MB
    float* colR = (float*)(ws + 393216 + 3 * 2097152);                         // 64 KB

    zero_prep<<<1072, 256, 0, stream>>>(out, Wq, Wk, Wv, Wt);
    qkv_gemm <<<512,  256, 0, stream>>>(x, Wt, qb, kb, vt);
    col_stats<<<1024, 256, 0, stream>>>(qb, kb, colR);
    attn_out <<<1024, 256, 0, stream>>>(qb, kb, vt, colR, out);
}

// Round 10
// 83.532 us; speedup vs baseline: 8.1543x; 1.0503x over previous
//
#include <hip/hip_runtime.h>
#include <hip/hip_bf16.h>

typedef __attribute__((ext_vector_type(8))) short short8;   // bf16x8 MFMA frag
typedef __attribute__((ext_vector_type(4))) float f32x4;    // fp32x4 acc

#define B_  8
#define T_  2048
#define E_  1024
#define H_  64
#define SCALE 0.03125f   // 1024^-0.5

__device__ inline unsigned short f2bf(float f) {
    unsigned int u = __builtin_bit_cast(unsigned int, f);
    unsigned int r = (u + 0x7FFFu + ((u >> 16) & 1u)) >> 16;   // RNE
    return (unsigned short)r;
}
__device__ inline unsigned int packbf(float lo, float hi) {
    return (unsigned int)f2bf(lo) | ((unsigned int)f2bf(hi) << 16);
}
__device__ inline void glds16(const void* g, void* l) {
    __builtin_amdgcn_global_load_lds((const __attribute__((address_space(1))) void*)g,
                                     (__attribute__((address_space(3))) void*)l, 16, 0, 0);
}

// ------------- kernel 0: fused {zero d_out (4MB)} + {W fp32 -> Wt bf16 transposed} ---
__global__ __launch_bounds__(256) void zero_prep(float* __restrict__ out,
                                                 const float* __restrict__ Wq,
                                                 const float* __restrict__ Wk,
                                                 const float* __restrict__ Wv,
                                                 unsigned short* __restrict__ Wt) {
    __shared__ float ls[64][65];
    if (blockIdx.x >= 48) {                       // zero part: 1024 blocks
        long bi = blockIdx.x - 48;
        uint4 z = (uint4){0u, 0u, 0u, 0u};
        *(uint4*)(out + (bi * 256 + threadIdx.x) * 4) = z;
        return;
    }
    int tid = threadIdx.x;
    int wsel = blockIdx.x >> 4, kt = blockIdx.x & 15;
    const float* W = (wsel == 0) ? Wq : (wsel == 1) ? Wk : Wv;
    int kr = tid >> 2, c4 = (tid & 3) * 16;
    const float* src = W + (long)(kt * 64 + kr) * H_ + c4;
    #pragma unroll
    for (int i = 0; i < 4; ++i) {
        float4 v = *(const float4*)(src + 4 * i);
        ls[kr][c4 + 4 * i + 0] = v.x; ls[kr][c4 + 4 * i + 1] = v.y;
        ls[kr][c4 + 4 * i + 2] = v.z; ls[kr][c4 + 4 * i + 3] = v.w;
    }
    __syncthreads();
    int c = tid >> 2, kk = (tid & 3) * 16;
    unsigned short* dst = Wt + (long)(wsel * 64 + c) * E_ + kt * 64 + kk;
    uint4 o1, o2;
    o1.x = packbf(ls[kk + 0][c], ls[kk + 1][c]);  o1.y = packbf(ls[kk + 2][c], ls[kk + 3][c]);
    o1.z = packbf(ls[kk + 4][c], ls[kk + 5][c]);  o1.w = packbf(ls[kk + 6][c], ls[kk + 7][c]);
    o2.x = packbf(ls[kk + 8][c], ls[kk + 9][c]);  o2.y = packbf(ls[kk + 10][c], ls[kk + 11][c]);
    o2.z = packbf(ls[kk + 12][c], ls[kk + 13][c]);o2.w = packbf(ls[kk + 14][c], ls[kk + 15][c]);
    *(uint4*)dst = o1;
    *(uint4*)(dst + 8) = o2;
}

// ---------------- kernel 1: QKV GEMM  [16384,1024] @ [1024,192] --------------------
// v3: 16-row blocks, grid 1024 = 4 blocks/CU (16 waves/CU TLP). 4 waves = 4-way
// col-split (48 cols each). W single-buffered LDS (m97 2-barrier pattern; cross-block
// overlap hides the drain). x dbuf, next-step x loaded under compute. LDS 29.2KB.
__global__ __launch_bounds__(256, 4) void qkv_gemm(const float* __restrict__ x,
                                                   const unsigned short* __restrict__ Wt,
                                                   unsigned short* __restrict__ qb,
                                                   unsigned short* __restrict__ kb,
                                                   unsigned short* __restrict__ vt) {
    __shared__ unsigned short wlds[192 * 64];      // 24576 B, single buffer (glds dest)
    __shared__ unsigned short xlds[2][16 * 72];    // 4608 B, padded stride 144B

    int tid = threadIdx.x, lane = tid & 63, w = tid >> 6;
    int l15 = lane & 15, lg = lane >> 4;
    int r0 = blockIdx.x * 16;
    int b = r0 >> 11, tb = r0 & 2047;

    // W staging: wave w stages Wt-rows 48w..48w+47 in 6 glds (8 rows x 8 chunks each);
    // source chunk pre-swizzled s8^l8, LDS linear (verified R7/R9 scheme).
    int l8 = lane >> 3, s8 = lane & 7;
    int swz = s8 ^ l8;
    const unsigned short* wg = Wt + (long)(48 * w + l8) * E_ + swz * 8;

    // x staging: thread -> row xr (16 rows), 4 floats at xcf
    int xr = tid >> 4, xcf = (tid & 15) * 4;
    const float* xg = x + (long)(r0 + xr) * E_ + xcf;

    f32x4 acc[3];
    #pragma unroll
    for (int i = 0; i < 3; ++i) acc[i] = (f32x4){0.f, 0.f, 0.f, 0.f};

    // prologue: x(0) -> xlds[0]
    {
        float4 xa = *(const float4*)xg;
        uint2 ua; ua.x = packbf(xa.x, xa.y); ua.y = packbf(xa.z, xa.w);
        *(uint2*)&xlds[0][xr * 72 + xcf] = ua;
    }

    for (int ks = 0; ks < 16; ++ks) {
        int cur = ks & 1;
        __builtin_amdgcn_s_barrier();              // b1: all waves done reading wlds/xlds
        __builtin_amdgcn_sched_barrier(0);
        {
            int kp = ks * 64;
            #pragma unroll
            for (int j = 0; j < 6; ++j)
                glds16(wg + (long)(8 * j) * E_ + kp, &wlds[(48 * w + 8 * j) * 64]);
        }
        asm volatile("s_waitcnt vmcnt(0) lgkmcnt(0)" ::: "memory");
        __builtin_amdgcn_sched_barrier(0);
        __builtin_amdgcn_s_barrier();              // b2: W(ks) ready everywhere
        __builtin_amdgcn_sched_barrier(0);

        // next-step x load flies under the MFMA phase
        float4 xa;
        if (ks < 15) xa = *(const float4*)(xg + (ks + 1) * 64);

        const char* xsb = (const char*)&xlds[cur][0];
        #pragma unroll
        for (int kk2 = 0; kk2 < 2; ++kk2) {
            short8 a = *(const short8*)(xsb + l15 * 144 + kk2 * 64 + lg * 16);
            #pragma unroll
            for (int ct = 0; ct < 3; ++ct) {
                int c = 48 * w + 16 * ct + l15;
                int sp = (kk2 * 4 + lg) ^ (c & 7);
                short8 bf = *(const short8*)((const char*)wlds + c * 128 + sp * 16);
                acc[ct] = __builtin_amdgcn_mfma_f32_16x16x32_bf16(a, bf, acc[ct], 0, 0, 0);
            }
        }
        if (ks < 15) {
            uint2 ua; ua.x = packbf(xa.x, xa.y); ua.y = packbf(xa.z, xa.w);
            *(uint2*)&xlds[cur ^ 1][xr * 72 + xcf] = ua;
        }
    }

    // q/k epilogue: cols 0..127 direct
    #pragma unroll
    for (int ct = 0; ct < 3; ++ct) {
        int col = 48 * w + 16 * ct + l15;
        if (col < 128) {
            unsigned short* dst = (col < 64) ? qb : kb;
            int n = col & 63;
            #pragma unroll
            for (int r = 0; r < 4; ++r) {
                int t = tb + lg * 4 + r;
                dst[((long)b * T_ + t) * H_ + n] = f2bf(acc[ct][r]);
            }
        }
    }
    // v epilogue (cols 128..191) via LDS transpose, reuse wlds
    __syncthreads();
    float* vbuf = (float*)&wlds[0];                // [16][68] fp32 = 4352B
    #pragma unroll
    for (int ct = 0; ct < 3; ++ct) {
        int col = 48 * w + 16 * ct + l15;
        if (col >= 128) {
            int h = col - 128;
            #pragma unroll
            for (int r = 0; r < 4; ++r)
                vbuf[(lg * 4 + r) * 68 + h] = acc[ct][r];
        }
    }
    __syncthreads();
    {
        int h = tid >> 2, tc = (tid & 3) * 4;
        uint2 o;
        o.x = packbf(vbuf[(tc + 0) * 68 + h], vbuf[(tc + 1) * 68 + h]);
        o.y = packbf(vbuf[(tc + 2) * 68 + h], vbuf[(tc + 3) * 68 + h]);
        *(uint2*)&vt[((long)b * H_ + h) * T_ + tb + tc] = o;
    }
}

// ---------------- kernel 2: per-key-column sum of exp(score) over t>=s ---------------
__global__ __launch_bounds__(256) void col_stats(const unsigned short* __restrict__ qb,
                                                 const unsigned short* __restrict__ kb,
                                                 float* __restrict__ colR) {
    __shared__ float lD[4][16];
    int tid = threadIdx.x, lane = tid & 63, w = tid >> 6;
    int b = blockIdx.x >> 7, c16 = blockIdx.x & 127;
    int sbase = c16 * 16;
    int l15 = lane & 15, lg = lane >> 4;

    const unsigned short* kp = kb + ((long)b * T_ + sbase + l15) * H_;
    short8 bk0 = *(const short8*)(kp + lg * 8);
    short8 bk1 = *(const short8*)(kp + 32 + lg * 8);

    float d1 = 0.f, d2 = 0.f;
    const unsigned short* qbase = qb + (long)b * T_ * H_;

    for (int t0 = sbase + 16 * w; t0 < T_; t0 += 128) {
        int t0b = t0 + 64;
        bool has2 = (t0b < T_);
        int t0c = has2 ? t0b : t0;
        const unsigned short* qp1 = qbase + (long)(t0 + l15) * H_ + lg * 8;
        const unsigned short* qp2 = qbase + (long)(t0c + l15) * H_ + lg * 8;
        short8 a0 = *(const short8*)qp1;
        short8 a1 = *(const short8*)(qp1 + 32);
        short8 c0 = *(const short8*)qp2;
        short8 c1 = *(const short8*)(qp2 + 32);

        f32x4 acc1 = (f32x4){0.f, 0.f, 0.f, 0.f};
        acc1 = __builtin_amdgcn_mfma_f32_16x16x32_bf16(a0, bk0, acc1, 0, 0, 0);
        acc1 = __builtin_amdgcn_mfma_f32_16x16x32_bf16(a1, bk1, acc1, 0, 0, 0);
        f32x4 acc2 = (f32x4){0.f, 0.f, 0.f, 0.f};
        acc2 = __builtin_amdgcn_mfma_f32_16x16x32_bf16(c0, bk0, acc2, 0, 0, 0);
        acc2 = __builtin_amdgcn_mfma_f32_16x16x32_bf16(c1, bk1, acc2, 0, 0, 0);

        #pragma unroll
        for (int r = 0; r < 4; ++r) {
            float e = __expf(acc1[r] * SCALE);
            if (t0 == sbase && (lg * 4 + r) < l15) e = 0.f;   // causal mask (diag tile)
            d1 += e;
        }
        if (has2) {
            #pragma unroll
            for (int r = 0; r < 4; ++r)
                d2 += __expf(acc2[r] * SCALE);
        }
    }
    float d = d1 + d2;
    d += __shfl_xor(d, 16, 64);
    d += __shfl_xor(d, 32, 64);
    if (lane < 16) lD[w][lane] = d;
    __syncthreads();
    if (tid < 16) {
        float df = lD[0][tid] + lD[1][tid] + lD[2][tid] + lD[3][tid];
        colR[b * T_ + sbase + tid] = 1.0f / df;
    }
}

// ---------------- kernel 3: out[t,h] = sum_{s<=t} exp(score)*R[s] * v[s,h] ----------
__global__ __launch_bounds__(256, 4) void attn_out(const unsigned short* __restrict__ qb,
                                                   const unsigned short* __restrict__ kb,
                                                   const unsigned short* __restrict__ vt,
                                                   const float* __restrict__ colR,
                                                   float* __restrict__ out) {
    __shared__ unsigned short kv[2][8192];        // [buf][ K 64x64 | V 64x64 ]  32 KB
    __shared__ unsigned short pbuf[4][16 * 40];   // per-wave P [16 q][32 s]      5 KB

    int tid = threadIdx.x, lane = tid & 63, w = tid >> 6;
    int qw = w & 1, sw = w >> 1;
    int l15 = lane & 15, lg = lane >> 4;
    int idx = blockIdx.x;
    int p = idx & 1;
    int b = (idx >> 1) & 7;
    int j = 63 - (idx >> 4);
    int t0 = j * 32;

    const unsigned short* kbase = kb + (long)b * T_ * H_;
    const unsigned short* vbase = vt + (long)b * H_ * T_;
    const float* cR = colR + b * T_;

    const unsigned short* qp = qb + ((long)b * T_ + t0 + qw * 16 + l15) * H_ + lg * 8;
    short8 qa0 = *(const short8*)qp;
    short8 qa1 = *(const short8*)(qp + 32);

    int l8 = lane >> 3, s8 = lane & 7;
    int swz8 = (s8 ^ l8) * 8;
    const unsigned short* kg = kbase + (long)(w * 16 + l8) * H_ + swz8;
    const unsigned short* vg = vbase + (long)(w * 16 + l8) * T_ + swz8;
    unsigned short* kd0 = &kv[0][w * 16 * 64];
    unsigned short* vd0 = &kv[0][4096 + w * 16 * 64];
    unsigned short* kd1 = &kv[1][w * 16 * 64];
    unsigned short* vd1 = &kv[1][4096 + w * 16 * 64];

    f32x4 o[4];
    #pragma unroll
    for (int i = 0; i < 4; ++i) o[i] = (f32x4){0.f, 0.f, 0.f, 0.f};
    unsigned short* myp = pbuf[w];

    int nstt = j / 2 + 1;

    if (p < nstt) {
        int s0 = p * 64;
        glds16(kg + (long)s0 * H_, kd0);  glds16(kg + (long)s0 * H_ + 8 * H_, kd0 + 8 * 64);
        glds16(vg + s0, vd0);             glds16(vg + s0 + 8 * T_, vd0 + 8 * 64);
    }

    int cnt = 0;
    for (int si = p; si < nstt; si += 2, ++cnt) {
        int cur = cnt & 1;
        __builtin_amdgcn_s_barrier();
        __builtin_amdgcn_sched_barrier(0);
        if (si + 2 < nstt) {
            int sn = (si + 2) * 64;
            unsigned short* kd = cur ? kd0 : kd1;
            unsigned short* vd = cur ? vd0 : vd1;
            glds16(kg + (long)sn * H_, kd);
            glds16(kg + (long)sn * H_ + 8 * H_, kd + 8 * 64);
            glds16(vg + sn, vd);
            glds16(vg + sn + 8 * T_, vd + 8 * 64);
            asm volatile("s_waitcnt vmcnt(4)" ::: "memory");
        } else {
            asm volatile("s_waitcnt vmcnt(0)" ::: "memory");
        }
        __builtin_amdgcn_sched_barrier(0);
        __builtin_amdgcn_s_barrier();
        __builtin_amdgcn_sched_barrier(0);

        int s0 = si * 64;
        const unsigned short* kt = &kv[cur][0];
        const unsigned short* vtl = &kv[cur][4096];

        #pragma unroll
        for (int ct = 0; ct < 2; ++ct) {
            int row = sw * 32 + ct * 16 + l15;
            short8 k0 = *(const short8*)&kt[row * 64 + ((0 + lg) ^ (row & 7)) * 8];
            short8 k1 = *(const short8*)&kt[row * 64 + ((4 + lg) ^ (row & 7)) * 8];
            f32x4 acc = (f32x4){0.f, 0.f, 0.f, 0.f};
            acc = __builtin_amdgcn_mfma_f32_16x16x32_bf16(qa0, k0, acc, 0, 0, 0);
            acc = __builtin_amdgcn_mfma_f32_16x16x32_bf16(qa1, k1, acc, 0, 0, 0);
            int s = s0 + row;
            float rr = cR[s];
            #pragma unroll
            for (int r = 0; r < 4; ++r) {
                int t = t0 + qw * 16 + lg * 4 + r;
                float pv = __expf(acc[r] * SCALE) * rr;
                if (s > t) pv = 0.f;
                myp[(lg * 4 + r) * 40 + ct * 16 + l15] = f2bf(pv);
            }
        }
        short8 pa = *(const short8*)&myp[l15 * 40 + lg * 8];
        #pragma unroll
        for (int ht = 0; ht < 4; ++ht) {
            int vrow = ht * 16 + l15;
            short8 vf = *(const short8*)&vtl[vrow * 64 + ((sw * 4 + lg) ^ (vrow & 7)) * 8];
            o[ht] = __builtin_amdgcn_mfma_f32_16x16x32_bf16(pa, vf, o[ht], 0, 0, 0);
        }
    }

    __syncthreads();
    float* rbuf = (float*)&kv[0][0];               // [32 q][68] f32
    if (sw == 1) {
        #pragma unroll
        for (int ht = 0; ht < 4; ++ht)
            #pragma unroll
            for (int r = 0; r < 4; ++r)
                rbuf[(qw * 16 + lg * 4 + r) * 68 + ht * 16 + l15] = o[ht][r];
    }
    __syncthreads();
    if (sw == 0) {
        float* ob = out + ((long)b * T_ + t0 + qw * 16) * H_;
        #pragma unroll
        for (int ht = 0; ht < 4; ++ht)
            #pragma unroll
            for (int r = 0; r < 4; ++r) {
                int rr_ = lg * 4 + r, cc = ht * 16 + l15;
                unsafeAtomicAdd(&ob[(long)rr_ * H_ + cc],
                                o[ht][r] + rbuf[(qw * 16 + rr_) * 68 + cc]);
            }
    }
}

extern "C" void kernel_launch(void* const* d_in, const int* in_sizes, int n_in,
                              void* d_out, int out_size, void* d_ws, size_t ws_size,
                              hipStream_t stream) {
    const float* x  = (const float*)d_in[0];
    const float* Wk = (const float*)d_in[1];
    const float* Wq = (const float*)d_in[2];
    const float* Wv = (const float*)d_in[3];
    float* out = (float*)d_out;

    char* ws = (char*)d_ws;
    unsigned short* Wt = (unsigned short*)ws;                                  // 393216 B
    unsigned short* qb = (unsigned short*)(ws + 393216);                       // 2 MB
    unsigned short* kb = (unsigned short*)(ws + 393216 + 2097152);             // 2 MB
    unsigned short* vt = (unsigned short*)(ws + 393216 + 2 * 2097152);         // 2 MB
    float* colR = (float*)(ws + 393216 + 3 * 2097152);                         // 64 KB

    zero_prep<<<1072, 256, 0, stream>>>(out, Wq, Wk, Wv, Wt);
    qkv_gemm <<<1024, 256, 0, stream>>>(x, Wt, qb, kb, vt);
    col_stats<<<1024, 256, 0, stream>>>(qb, kb, colR);
    attn_out <<<1024, 256, 0, stream>>>(qb, kb, vt, colR, out);
}

// Round 11
// 82.533 us; speedup vs baseline: 8.2530x; 1.0121x over previous
//
#include <hip/hip_runtime.h>
#include <hip/hip_bf16.h>

typedef __attribute__((ext_vector_type(8))) short short8;   // bf16x8 MFMA frag
typedef __attribute__((ext_vector_type(4))) float f32x4;    // fp32x4 acc

#define B_  8
#define T_  2048
#define E_  1024
#define H_  64
#define SCALE 0.03125f   // 1024^-0.5

__device__ inline unsigned short f2bf(float f) {
    unsigned int u = __builtin_bit_cast(unsigned int, f);
    unsigned int r = (u + 0x7FFFu + ((u >> 16) & 1u)) >> 16;   // RNE
    return (unsigned short)r;
}
__device__ inline unsigned int packbf(float lo, float hi) {
    return (unsigned int)f2bf(lo) | ((unsigned int)f2bf(hi) << 16);
}
__device__ inline void glds16(const void* g, void* l) {
    __builtin_amdgcn_global_load_lds((const __attribute__((address_space(1))) void*)g,
                                     (__attribute__((address_space(3))) void*)l, 16, 0, 0);
}

// ------------- kernel 0: fused {zero d_out (4MB)} + {W fp32 -> Wt bf16 transposed} ---
__global__ __launch_bounds__(256) void zero_prep(float* __restrict__ out,
                                                 const float* __restrict__ Wq,
                                                 const float* __restrict__ Wk,
                                                 const float* __restrict__ Wv,
                                                 unsigned short* __restrict__ Wt) {
    __shared__ float ls[64][65];
    if (blockIdx.x >= 48) {                       // zero part: 1024 blocks
        long bi = blockIdx.x - 48;
        uint4 z = (uint4){0u, 0u, 0u, 0u};
        *(uint4*)(out + (bi * 256 + threadIdx.x) * 4) = z;
        return;
    }
    int tid = threadIdx.x;
    int wsel = blockIdx.x >> 4, kt = blockIdx.x & 15;
    const float* W = (wsel == 0) ? Wq : (wsel == 1) ? Wk : Wv;
    int kr = tid >> 2, c4 = (tid & 3) * 16;
    const float* src = W + (long)(kt * 64 + kr) * H_ + c4;
    #pragma unroll
    for (int i = 0; i < 4; ++i) {
        float4 v = *(const float4*)(src + 4 * i);
        ls[kr][c4 + 4 * i + 0] = v.x; ls[kr][c4 + 4 * i + 1] = v.y;
        ls[kr][c4 + 4 * i + 2] = v.z; ls[kr][c4 + 4 * i + 3] = v.w;
    }
    __syncthreads();
    int c = tid >> 2, kk = (tid & 3) * 16;
    unsigned short* dst = Wt + (long)(wsel * 64 + c) * E_ + kt * 64 + kk;
    uint4 o1, o2;
    o1.x = packbf(ls[kk + 0][c], ls[kk + 1][c]);  o1.y = packbf(ls[kk + 2][c], ls[kk + 3][c]);
    o1.z = packbf(ls[kk + 4][c], ls[kk + 5][c]);  o1.w = packbf(ls[kk + 6][c], ls[kk + 7][c]);
    o2.x = packbf(ls[kk + 8][c], ls[kk + 9][c]);  o2.y = packbf(ls[kk + 10][c], ls[kk + 11][c]);
    o2.z = packbf(ls[kk + 12][c], ls[kk + 13][c]);o2.w = packbf(ls[kk + 14][c], ls[kk + 15][c]);
    *(uint4*)dst = o1;
    *(uint4*)(dst + 8) = o2;
}

// ---------------- kernel 1: QKV GEMM  [16384,1024] @ [1024,192] --------------------
// v4 = v3 + k-loop PHASE STAGGER: block bid walks W chunks in order (ks + bid%16)&15,
// spreading the grid across all 384KB of Wt (kills the L2 sector hotspot convoy).
__global__ __launch_bounds__(256, 4) void qkv_gemm(const float* __restrict__ x,
                                                   const unsigned short* __restrict__ Wt,
                                                   unsigned short* __restrict__ qb,
                                                   unsigned short* __restrict__ kb,
                                                   unsigned short* __restrict__ vt) {
    __shared__ unsigned short wlds[192 * 64];      // 24576 B, single buffer (glds dest)
    __shared__ unsigned short xlds[2][16 * 72];    // 4608 B, padded stride 144B

    int tid = threadIdx.x, lane = tid & 63, w = tid >> 6;
    int l15 = lane & 15, lg = lane >> 4;
    int r0 = blockIdx.x * 16;
    int b = r0 >> 11, tb = r0 & 2047;
    int phase = blockIdx.x & 15;

    int l8 = lane >> 3, s8 = lane & 7;
    int swz = s8 ^ l8;
    const unsigned short* wg = Wt + (long)(48 * w + l8) * E_ + swz * 8;

    int xr = tid >> 4, xcf = (tid & 15) * 4;
    const float* xg = x + (long)(r0 + xr) * E_ + xcf;

    f32x4 acc[3];
    #pragma unroll
    for (int i = 0; i < 3; ++i) acc[i] = (f32x4){0.f, 0.f, 0.f, 0.f};

    // prologue: x(step phase) -> xlds[0]
    {
        float4 xa = *(const float4*)(xg + phase * 64);
        uint2 ua; ua.x = packbf(xa.x, xa.y); ua.y = packbf(xa.z, xa.w);
        *(uint2*)&xlds[0][xr * 72 + xcf] = ua;
    }

    for (int ks = 0; ks < 16; ++ks) {
        int cur = ks & 1;
        int kcur = ((ks + phase) & 15) * 64;
        __builtin_amdgcn_s_barrier();              // b1: all waves done reading wlds/xlds
        __builtin_amdgcn_sched_barrier(0);
        {
            #pragma unroll
            for (int j = 0; j < 6; ++j)
                glds16(wg + (long)(8 * j) * E_ + kcur, &wlds[(48 * w + 8 * j) * 64]);
        }
        asm volatile("s_waitcnt vmcnt(0) lgkmcnt(0)" ::: "memory");
        __builtin_amdgcn_sched_barrier(0);
        __builtin_amdgcn_s_barrier();              // b2: W(kcur) ready everywhere
        __builtin_amdgcn_sched_barrier(0);

        // next-step x load flies under the MFMA phase
        float4 xa;
        if (ks < 15) xa = *(const float4*)(xg + (((ks + 1 + phase) & 15)) * 64);

        const char* xsb = (const char*)&xlds[cur][0];
        #pragma unroll
        for (int kk2 = 0; kk2 < 2; ++kk2) {
            short8 a = *(const short8*)(xsb + l15 * 144 + kk2 * 64 + lg * 16);
            #pragma unroll
            for (int ct = 0; ct < 3; ++ct) {
                int c = 48 * w + 16 * ct + l15;
                int sp = (kk2 * 4 + lg) ^ (c & 7);
                short8 bf = *(const short8*)((const char*)wlds + c * 128 + sp * 16);
                acc[ct] = __builtin_amdgcn_mfma_f32_16x16x32_bf16(a, bf, acc[ct], 0, 0, 0);
            }
        }
        if (ks < 15) {
            uint2 ua; ua.x = packbf(xa.x, xa.y); ua.y = packbf(xa.z, xa.w);
            *(uint2*)&xlds[cur ^ 1][xr * 72 + xcf] = ua;
        }
    }

    // q/k epilogue: cols 0..127 direct
    #pragma unroll
    for (int ct = 0; ct < 3; ++ct) {
        int col = 48 * w + 16 * ct + l15;
        if (col < 128) {
            unsigned short* dst = (col < 64) ? qb : kb;
            int n = col & 63;
            #pragma unroll
            for (int r = 0; r < 4; ++r) {
                int t = tb + lg * 4 + r;
                dst[((long)b * T_ + t) * H_ + n] = f2bf(acc[ct][r]);
            }
        }
    }
    // v epilogue (cols 128..191) via LDS transpose, reuse wlds
    __syncthreads();
    float* vbuf = (float*)&wlds[0];                // [16][68] fp32 = 4352B
    #pragma unroll
    for (int ct = 0; ct < 3; ++ct) {
        int col = 48 * w + 16 * ct + l15;
        if (col >= 128) {
            int h = col - 128;
            #pragma unroll
            for (int r = 0; r < 4; ++r)
                vbuf[(lg * 4 + r) * 68 + h] = acc[ct][r];
        }
    }
    __syncthreads();
    {
        int h = tid >> 2, tc = (tid & 3) * 4;
        uint2 o;
        o.x = packbf(vbuf[(tc + 0) * 68 + h], vbuf[(tc + 1) * 68 + h]);
        o.y = packbf(vbuf[(tc + 2) * 68 + h], vbuf[(tc + 3) * 68 + h]);
        *(uint2*)&vt[((long)b * H_ + h) * T_ + tb + tc] = o;
    }
}

// ---------------- kernel 2: per-key-column sum of exp(score) over t>=s ---------------
__global__ __launch_bounds__(256) void col_stats(const unsigned short* __restrict__ qb,
                                                 const unsigned short* __restrict__ kb,
                                                 float* __restrict__ colR) {
    __shared__ float lD[4][16];
    int tid = threadIdx.x, lane = tid & 63, w = tid >> 6;
    int b = blockIdx.x >> 7, c16 = blockIdx.x & 127;
    int sbase = c16 * 16;
    int l15 = lane & 15, lg = lane >> 4;

    const unsigned short* kp = kb + ((long)b * T_ + sbase + l15) * H_;
    short8 bk0 = *(const short8*)(kp + lg * 8);
    short8 bk1 = *(const short8*)(kp + 32 + lg * 8);

    float d1 = 0.f, d2 = 0.f;
    const unsigned short* qbase = qb + (long)b * T_ * H_;

    for (int t0 = sbase + 16 * w; t0 < T_; t0 += 128) {
        int t0b = t0 + 64;
        bool has2 = (t0b < T_);
        int t0c = has2 ? t0b : t0;
        const unsigned short* qp1 = qbase + (long)(t0 + l15) * H_ + lg * 8;
        const unsigned short* qp2 = qbase + (long)(t0c + l15) * H_ + lg * 8;
        short8 a0 = *(const short8*)qp1;
        short8 a1 = *(const short8*)(qp1 + 32);
        short8 c0 = *(const short8*)qp2;
        short8 c1 = *(const short8*)(qp2 + 32);

        f32x4 acc1 = (f32x4){0.f, 0.f, 0.f, 0.f};
        acc1 = __builtin_amdgcn_mfma_f32_16x16x32_bf16(a0, bk0, acc1, 0, 0, 0);
        acc1 = __builtin_amdgcn_mfma_f32_16x16x32_bf16(a1, bk1, acc1, 0, 0, 0);
        f32x4 acc2 = (f32x4){0.f, 0.f, 0.f, 0.f};
        acc2 = __builtin_amdgcn_mfma_f32_16x16x32_bf16(c0, bk0, acc2, 0, 0, 0);
        acc2 = __builtin_amdgcn_mfma_f32_16x16x32_bf16(c1, bk1, acc2, 0, 0, 0);

        #pragma unroll
        for (int r = 0; r < 4; ++r) {
            float e = __expf(acc1[r] * SCALE);
            if (t0 == sbase && (lg * 4 + r) < l15) e = 0.f;   // causal mask (diag tile)
            d1 += e;
        }
        if (has2) {
            #pragma unroll
            for (int r = 0; r < 4; ++r)
                d2 += __expf(acc2[r] * SCALE);
        }
    }
    float d = d1 + d2;
    d += __shfl_xor(d, 16, 64);
    d += __shfl_xor(d, 32, 64);
    if (lane < 16) lD[w][lane] = d;
    __syncthreads();
    if (tid < 16) {
        float df = lD[0][tid] + lD[1][tid] + lD[2][tid] + lD[3][tid];
        colR[b * T_ + sbase + tid] = 1.0f / df;
    }
}

// ---------------- kernel 3: out[t,h] = sum_{s<=t} exp(score)*R[s] * v[s,h] ----------
// v2 = + s-tile rotation (off = j%m): blocks sharing (b,p) start at different tiles,
// spreading K/V L2 sector traffic. Accumulation order fixed per block -> deterministic.
__global__ __launch_bounds__(256, 4) void attn_out(const unsigned short* __restrict__ qb,
                                                   const unsigned short* __restrict__ kb,
                                                   const unsigned short* __restrict__ vt,
                                                   const float* __restrict__ colR,
                                                   float* __restrict__ out) {
    __shared__ unsigned short kv[2][8192];        // [buf][ K 64x64 | V 64x64 ]  32 KB
    __shared__ unsigned short pbuf[4][16 * 40];   // per-wave P [16 q][32 s]      5 KB

    int tid = threadIdx.x, lane = tid & 63, w = tid >> 6;
    int qw = w & 1, sw = w >> 1;
    int l15 = lane & 15, lg = lane >> 4;
    int idx = blockIdx.x;
    int p = idx & 1;
    int b = (idx >> 1) & 7;
    int j = 63 - (idx >> 4);
    int t0 = j * 32;

    const unsigned short* kbase = kb + (long)b * T_ * H_;
    const unsigned short* vbase = vt + (long)b * H_ * T_;
    const float* cR = colR + b * T_;

    const unsigned short* qp = qb + ((long)b * T_ + t0 + qw * 16 + l15) * H_ + lg * 8;
    short8 qa0 = *(const short8*)qp;
    short8 qa1 = *(const short8*)(qp + 32);

    int l8 = lane >> 3, s8 = lane & 7;
    int swz8 = (s8 ^ l8) * 8;
    const unsigned short* kg = kbase + (long)(w * 16 + l8) * H_ + swz8;
    const unsigned short* vg = vbase + (long)(w * 16 + l8) * T_ + swz8;
    unsigned short* kd0 = &kv[0][w * 16 * 64];
    unsigned short* vd0 = &kv[0][4096 + w * 16 * 64];
    unsigned short* kd1 = &kv[1][w * 16 * 64];
    unsigned short* vd1 = &kv[1][4096 + w * 16 * 64];

    f32x4 o[4];
    #pragma unroll
    for (int i = 0; i < 4; ++i) o[i] = (f32x4){0.f, 0.f, 0.f, 0.f};
    unsigned short* myp = pbuf[w];

    int nstt = j / 2 + 1;
    int m = (nstt - p + 1) >> 1;                  // # of s-tiles for this block
    int off = (m > 0) ? (j % m) : 0;              // per-block rotation

    if (m > 0) {                                  // prologue: stage first rotated tile
        int s0 = (p + 2 * off) * 64;
        glds16(kg + (long)s0 * H_, kd0);  glds16(kg + (long)s0 * H_ + 8 * H_, kd0 + 8 * 64);
        glds16(vg + s0, vd0);             glds16(vg + s0 + 8 * T_, vd0 + 8 * 64);
    }

    for (int i = 0; i < m; ++i) {
        int cur = i & 1;
        __builtin_amdgcn_s_barrier();
        __builtin_amdgcn_sched_barrier(0);
        if (i + 1 < m) {
            int rot = i + 1 + off; if (rot >= m) rot -= m;
            int sn = (p + 2 * rot) * 64;
            unsigned short* kd = cur ? kd0 : kd1;
            unsigned short* vd = cur ? vd0 : vd1;
            glds16(kg + (long)sn * H_, kd);
            glds16(kg + (long)sn * H_ + 8 * H_, kd + 8 * 64);
            glds16(vg + sn, vd);
            glds16(vg + sn + 8 * T_, vd + 8 * 64);
            asm volatile("s_waitcnt vmcnt(4)" ::: "memory");
        } else {
            asm volatile("s_waitcnt vmcnt(0)" ::: "memory");
        }
        __builtin_amdgcn_sched_barrier(0);
        __builtin_amdgcn_s_barrier();
        __builtin_amdgcn_sched_barrier(0);

        int rotc = i + off; if (rotc >= m) rotc -= m;
        int s0 = (p + 2 * rotc) * 64;
        const unsigned short* kt = &kv[cur][0];
        const unsigned short* vtl = &kv[cur][4096];

        #pragma unroll
        for (int ct = 0; ct < 2; ++ct) {
            int row = sw * 32 + ct * 16 + l15;
            short8 k0 = *(const short8*)&kt[row * 64 + ((0 + lg) ^ (row & 7)) * 8];
            short8 k1 = *(const short8*)&kt[row * 64 + ((4 + lg) ^ (row & 7)) * 8];
            f32x4 acc = (f32x4){0.f, 0.f, 0.f, 0.f};
            acc = __builtin_amdgcn_mfma_f32_16x16x32_bf16(qa0, k0, acc, 0, 0, 0);
            acc = __builtin_amdgcn_mfma_f32_16x16x32_bf16(qa1, k1, acc, 0, 0, 0);
            int s = s0 + row;
            float rr = cR[s];
            #pragma unroll
            for (int r = 0; r < 4; ++r) {
                int t = t0 + qw * 16 + lg * 4 + r;
                float pv = __expf(acc[r] * SCALE) * rr;
                if (s > t) pv = 0.f;
                myp[(lg * 4 + r) * 40 + ct * 16 + l15] = f2bf(pv);
            }
        }
        short8 pa = *(const short8*)&myp[l15 * 40 + lg * 8];
        #pragma unroll
        for (int ht = 0; ht < 4; ++ht) {
            int vrow = ht * 16 + l15;
            short8 vf = *(const short8*)&vtl[vrow * 64 + ((sw * 4 + lg) ^ (vrow & 7)) * 8];
            o[ht] = __builtin_amdgcn_mfma_f32_16x16x32_bf16(pa, vf, o[ht], 0, 0, 0);
        }
    }

    __syncthreads();
    float* rbuf = (float*)&kv[0][0];               // [32 q][68] f32
    if (sw == 1) {
        #pragma unroll
        for (int ht = 0; ht < 4; ++ht)
            #pragma unroll
            for (int r = 0; r < 4; ++r)
                rbuf[(qw * 16 + lg * 4 + r) * 68 + ht * 16 + l15] = o[ht][r];
    }
    __syncthreads();
    if (sw == 0) {
        float* ob = out + ((long)b * T_ + t0 + qw * 16) * H_;
        #pragma unroll
        for (int ht = 0; ht < 4; ++ht)
            #pragma unroll
            for (int r = 0; r < 4; ++r) {
                int rr_ = lg * 4 + r, cc = ht * 16 + l15;
                unsafeAtomicAdd(&ob[(long)rr_ * H_ + cc],
                                o[ht][r] + rbuf[(qw * 16 + rr_) * 68 + cc]);
            }
    }
}

extern "C" void kernel_launch(void* const* d_in, const int* in_sizes, int n_in,
                              void* d_out, int out_size, void* d_ws, size_t ws_size,
                              hipStream_t stream) {
    const float* x  = (const float*)d_in[0];
    const float* Wk = (const float*)d_in[1];
    const float* Wq = (const float*)d_in[2];
    const float* Wv = (const float*)d_in[3];
    float* out = (float*)d_out;

    char* ws = (char*)d_ws;
    unsigned short* Wt = (unsigned short*)ws;                                  // 393216 B
    unsigned short* qb = (unsigned short*)(ws + 393216);                       // 2 MB
    unsigned short* kb = (unsigned short*)(ws + 393216 + 2097152);             // 2 MB
    unsigned short* vt = (unsigned short*)(ws + 393216 + 2 * 2097152);         // 2 MB
    float* colR = (float*)(ws + 393216 + 3 * 2097152);                         // 64 KB

    zero_prep<<<1072, 256, 0, stream>>>(out, Wq, Wk, Wv, Wt);
    qkv_gemm <<<1024, 256, 0, stream>>>(x, Wt, qb, kb, vt);
    col_stats<<<1024, 256, 0, stream>>>(qb, kb, colR);
    attn_out <<<1024, 256, 0, stream>>>(qb, kb, vt, colR, out);
}

// Round 14
// 76.895 us; speedup vs baseline: 8.8582x; 1.0733x over previous
//
#include <hip/hip_runtime.h>
#include <hip/hip_bf16.h>

typedef __attribute__((ext_vector_type(8))) short short8;   // bf16x8 MFMA frag
typedef __attribute__((ext_vector_type(4))) float f32x4;    // fp32x4 acc

#define B_  8
#define T_  2048
#define E_  1024
#define H_  64
#define SCALE 0.03125f   // 1024^-0.5

__device__ inline unsigned short f2bf(float f) {
    unsigned int u = __builtin_bit_cast(unsigned int, f);
    unsigned int r = (u + 0x7FFFu + ((u >> 16) & 1u)) >> 16;   // RNE
    return (unsigned short)r;
}
__device__ inline unsigned int packbf(float lo, float hi) {
    return (unsigned int)f2bf(lo) | ((unsigned int)f2bf(hi) << 16);
}
__device__ inline void glds16(const void* g, void* l) {
    __builtin_amdgcn_global_load_lds((const __attribute__((address_space(1))) void*)g,
                                     (__attribute__((address_space(3))) void*)l, 16, 0, 0);
}

// ------------- kernel 0: fused {zero d_out (4MB)} + {W fp32 -> Wt bf16 transposed} ---
__global__ __launch_bounds__(256) void zero_prep(float* __restrict__ out,
                                                 const float* __restrict__ Wq,
                                                 const float* __restrict__ Wk,
                                                 const float* __restrict__ Wv,
                                                 unsigned short* __restrict__ Wt) {
    __shared__ float ls[64][65];
    if (blockIdx.x >= 48) {                       // zero part: 1024 blocks
        long bi = blockIdx.x - 48;
        uint4 z = (uint4){0u, 0u, 0u, 0u};
        *(uint4*)(out + (bi * 256 + threadIdx.x) * 4) = z;
        return;
    }
    int tid = threadIdx.x;
    int wsel = blockIdx.x >> 4, kt = blockIdx.x & 15;
    const float* W = (wsel == 0) ? Wq : (wsel == 1) ? Wk : Wv;
    int kr = tid >> 2, c4 = (tid & 3) * 16;
    const float* src = W + (long)(kt * 64 + kr) * H_ + c4;
    #pragma unroll
    for (int i = 0; i < 4; ++i) {
        float4 v = *(const float4*)(src + 4 * i);
        ls[kr][c4 + 4 * i + 0] = v.x; ls[kr][c4 + 4 * i + 1] = v.y;
        ls[kr][c4 + 4 * i + 2] = v.z; ls[kr][c4 + 4 * i + 3] = v.w;
    }
    __syncthreads();
    int c = tid >> 2, kk = (tid & 3) * 16;
    unsigned short* dst = Wt + (long)(wsel * 64 + c) * E_ + kt * 64 + kk;
    uint4 o1, o2;
    o1.x = packbf(ls[kk + 0][c], ls[kk + 1][c]);  o1.y = packbf(ls[kk + 2][c], ls[kk + 3][c]);
    o1.z = packbf(ls[kk + 4][c], ls[kk + 5][c]);  o1.w = packbf(ls[kk + 6][c], ls[kk + 7][c]);
    o2.x = packbf(ls[kk + 8][c], ls[kk + 9][c]);  o2.y = packbf(ls[kk + 10][c], ls[kk + 11][c]);
    o2.z = packbf(ls[kk + 12][c], ls[kk + 13][c]);o2.w = packbf(ls[kk + 14][c], ls[kk + 15][c]);
    *(uint4*)dst = o1;
    *(uint4*)(dst + 8) = o2;
}

// ---------------- kernel 1: QKV GEMM  [16384,1024] @ [1024,192] --------------------
// R7 version (verified across R7/R9/R10/R11): 32 rows x 192 cols, BK=64, W dbuf via
// glds, rolling counted vmcnt(8) = prev step's {2 x-loads + 6 glds} drained, this
// step's 8 stay in flight. 2 barriers/step.
__global__ __launch_bounds__(256) void qkv_gemm(const float* __restrict__ x,
                                                const unsigned short* __restrict__ Wt,
                                                unsigned short* __restrict__ qb,
                                                unsigned short* __restrict__ kb,
                                                unsigned short* __restrict__ vt) {
    __shared__ unsigned short wlds[2][192 * 64];   // 49152 B, linear (glds dest)
    __shared__ unsigned short xlds[2][32 * 72];    // 9216 B, padded stride 144B

    int tid = threadIdx.x, lane = tid & 63, w = tid >> 6;
    int l15 = lane & 15, lg = lane >> 4;
    int wr = w & 1, wc = w >> 1;
    int r0 = blockIdx.x * 32;
    int b = r0 >> 11, tb = r0 & 2047;

    int l8 = lane >> 3, s8 = lane & 7;
    int swz = s8 ^ l8;
    const unsigned short* wg = Wt + (long)(48 * w + l8) * E_ + swz * 8;
    unsigned short* wl0 = &wlds[0][(48 * w) * 64];
    unsigned short* wl1 = &wlds[1][(48 * w) * 64];

    int xr = tid >> 3, xc = tid & 7;
    const float* xg = x + (long)(r0 + xr) * E_ + xc * 8;

    f32x4 acc[6];
    #pragma unroll
    for (int i = 0; i < 6; ++i) acc[i] = (f32x4){0.f, 0.f, 0.f, 0.f};

    {
        float4 xa = *(const float4*)xg;
        float4 xb = *(const float4*)(xg + 4);
        #pragma unroll
        for (int j = 0; j < 6; ++j)
            glds16(wg + (long)(8 * j) * E_, wl0 + (8 * j) * 64);
        uint4 ua;
        ua.x = packbf(xa.x, xa.y); ua.y = packbf(xa.z, xa.w);
        ua.z = packbf(xb.x, xb.y); ua.w = packbf(xb.z, xb.w);
        *(uint4*)((char*)&xlds[0][0] + xr * 144 + xc * 16) = ua;
    }

    for (int ks = 0; ks < 16; ++ks) {
        int cur = ks & 1;
        __builtin_amdgcn_s_barrier();
        __builtin_amdgcn_sched_barrier(0);
        float4 xa, xb;
        if (ks < 15) {
            int kp = (ks + 1) * 64;
            xa = *(const float4*)(xg + kp);
            xb = *(const float4*)(xg + kp + 4);
            unsigned short* wldst = cur ? wl0 : wl1;
            #pragma unroll
            for (int j = 0; j < 6; ++j)
                glds16(wg + (long)(8 * j) * E_ + kp, wldst + (8 * j) * 64);
            asm volatile("s_waitcnt vmcnt(8) lgkmcnt(0)" ::: "memory");
        } else {
            asm volatile("s_waitcnt vmcnt(0) lgkmcnt(0)" ::: "memory");
        }
        __builtin_amdgcn_sched_barrier(0);
        __builtin_amdgcn_s_barrier();
        __builtin_amdgcn_sched_barrier(0);

        const char* wb = (const char*)&wlds[cur][0];
        const char* xsb = (const char*)&xlds[cur][0];
        #pragma unroll
        for (int kk2 = 0; kk2 < 2; ++kk2) {
            short8 a = *(const short8*)(xsb + (16 * wr + l15) * 144 + kk2 * 64 + lg * 16);
            #pragma unroll
            for (int ct = 0; ct < 6; ++ct) {
                int c = 96 * wc + 16 * ct + l15;
                int sp = (kk2 * 4 + lg) ^ (c & 7);
                short8 bf = *(const short8*)(wb + c * 128 + sp * 16);
                acc[ct] = __builtin_amdgcn_mfma_f32_16x16x32_bf16(a, bf, acc[ct], 0, 0, 0);
            }
        }
        if (ks < 15) {
            uint4 ua;
            ua.x = packbf(xa.x, xa.y); ua.y = packbf(xa.z, xa.w);
            ua.z = packbf(xb.x, xb.y); ua.w = packbf(xb.z, xb.w);
            *(uint4*)((char*)&xlds[cur ^ 1][0] + xr * 144 + xc * 16) = ua;
        }
    }

    #pragma unroll
    for (int ct = 0; ct < 6; ++ct) {
        int col = 96 * wc + 16 * ct + l15;
        if (col < 128) {
            unsigned short* dst = (col < 64) ? qb : kb;
            int n = col & 63;
            #pragma unroll
            for (int r = 0; r < 4; ++r) {
                int t = tb + 16 * wr + lg * 4 + r;
                dst[((long)b * T_ + t) * H_ + n] = f2bf(acc[ct][r]);
            }
        }
    }
    float* vbuf = (float*)&wlds[0][0];
    if (wc == 1) {
        #pragma unroll
        for (int ct = 2; ct < 6; ++ct) {
            int h = 16 * (ct - 2) + l15;
            #pragma unroll
            for (int r = 0; r < 4; ++r)
                vbuf[(16 * wr + lg * 4 + r) * 68 + h] = acc[ct][r];
        }
    }
    __syncthreads();
    {
        int h = tid >> 2, tc = (tid & 3) * 8;
        uint4 o;
        o.x = packbf(vbuf[(tc + 0) * 68 + h], vbuf[(tc + 1) * 68 + h]);
        o.y = packbf(vbuf[(tc + 2) * 68 + h], vbuf[(tc + 3) * 68 + h]);
        o.z = packbf(vbuf[(tc + 4) * 68 + h], vbuf[(tc + 5) * 68 + h]);
        o.w = packbf(vbuf[(tc + 6) * 68 + h], vbuf[(tc + 7) * 68 + h]);
        *(uint4*)&vt[((long)b * H_ + h) * T_ + tb + tc] = o;
    }
}

// ---------------- kernel 2: per-key-column sum of exp(score) over t>=s ---------------
__global__ __launch_bounds__(256) void col_stats(const unsigned short* __restrict__ qb,
                                                 const unsigned short* __restrict__ kb,
                                                 float* __restrict__ colR) {
    __shared__ float lD[4][16];
    int tid = threadIdx.x, lane = tid & 63, w = tid >> 6;
    int b = blockIdx.x >> 7, c16 = blockIdx.x & 127;
    int sbase = c16 * 16;
    int l15 = lane & 15, lg = lane >> 4;

    const unsigned short* kp = kb + ((long)b * T_ + sbase + l15) * H_;
    short8 bk0 = *(const short8*)(kp + lg * 8);
    short8 bk1 = *(const short8*)(kp + 32 + lg * 8);

    float d1 = 0.f, d2 = 0.f;
    const unsigned short* qbase = qb + (long)b * T_ * H_;

    for (int t0 = sbase + 16 * w; t0 < T_; t0 += 128) {
        int t0b = t0 + 64;
        bool has2 = (t0b < T_);
        int t0c = has2 ? t0b : t0;
        const unsigned short* qp1 = qbase + (long)(t0 + l15) * H_ + lg * 8;
        const unsigned short* qp2 = qbase + (long)(t0c + l15) * H_ + lg * 8;
        short8 a0 = *(const short8*)qp1;
        short8 a1 = *(const short8*)(qp1 + 32);
        short8 c0 = *(const short8*)qp2;
        short8 c1 = *(const short8*)(qp2 + 32);

        f32x4 acc1 = (f32x4){0.f, 0.f, 0.f, 0.f};
        acc1 = __builtin_amdgcn_mfma_f32_16x16x32_bf16(a0, bk0, acc1, 0, 0, 0);
        acc1 = __builtin_amdgcn_mfma_f32_16x16x32_bf16(a1, bk1, acc1, 0, 0, 0);
        f32x4 acc2 = (f32x4){0.f, 0.f, 0.f, 0.f};
        acc2 = __builtin_amdgcn_mfma_f32_16x16x32_bf16(c0, bk0, acc2, 0, 0, 0);
        acc2 = __builtin_amdgcn_mfma_f32_16x16x32_bf16(c1, bk1, acc2, 0, 0, 0);

        #pragma unroll
        for (int r = 0; r < 4; ++r) {
            float e = __expf(acc1[r] * SCALE);
            if (t0 == sbase && (lg * 4 + r) < l15) e = 0.f;   // causal mask (diag tile)
            d1 += e;
        }
        if (has2) {
            #pragma unroll
            for (int r = 0; r < 4; ++r)
                d2 += __expf(acc2[r] * SCALE);
        }
    }
    float d = d1 + d2;
    d += __shfl_xor(d, 16, 64);
    d += __shfl_xor(d, 32, 64);
    if (lane < 16) lD[w][lane] = d;
    __syncthreads();
    if (tid < 16) {
        float df = lD[0][tid] + lD[1][tid] + lD[2][tid] + lD[3][tid];
        colR[b * T_ + sbase + tid] = 1.0f / df;
    }
}

// ---------------- kernel 3: out[t,h] = sum_{s<=t} exp(score)*R[s] * v[s,h] ----------
__global__ __launch_bounds__(256, 4) void attn_out(const unsigned short* __restrict__ qb,
                                                   const unsigned short* __restrict__ kb,
                                                   const unsigned short* __restrict__ vt,
                                                   const float* __restrict__ colR,
                                                   float* __restrict__ out) {
    __shared__ unsigned short kv[2][8192];        // [buf][ K 64x64 | V 64x64 ]  32 KB
    __shared__ unsigned short pbuf[4][16 * 40];   // per-wave P [16 q][32 s]      5 KB

    int tid = threadIdx.x, lane = tid & 63, w = tid >> 6;
    int qw = w & 1, sw = w >> 1;
    int l15 = lane & 15, lg = lane >> 4;
    int idx = blockIdx.x;
    int p = idx & 1;
    int b = (idx >> 1) & 7;
    int j = 63 - (idx >> 4);
    int t0 = j * 32;

    const unsigned short* kbase = kb + (long)b * T_ * H_;
    const unsigned short* vbase = vt + (long)b * H_ * T_;
    const float* cR = colR + b * T_;

    const unsigned short* qp = qb + ((long)b * T_ + t0 + qw * 16 + l15) * H_ + lg * 8;
    short8 qa0 = *(const short8*)qp;
    short8 qa1 = *(const short8*)(qp + 32);

    int l8 = lane >> 3, s8 = lane & 7;
    int swz8 = (s8 ^ l8) * 8;
    const unsigned short* kg = kbase + (long)(w * 16 + l8) * H_ + swz8;
    const unsigned short* vg = vbase + (long)(w * 16 + l8) * T_ + swz8;
    unsigned short* kd0 = &kv[0][w * 16 * 64];
    unsigned short* vd0 = &kv[0][4096 + w * 16 * 64];
    unsigned short* kd1 = &kv[1][w * 16 * 64];
    unsigned short* vd1 = &kv[1][4096 + w * 16 * 64];

    f32x4 o[4];
    #pragma unroll
    for (int i = 0; i < 4; ++i) o[i] = (f32x4){0.f, 0.f, 0.f, 0.f};
    unsigned short* myp = pbuf[w];

    int nstt = j / 2 + 1;
    int m = (nstt - p + 1) >> 1;                  // # of s-tiles for this block
    int off = (m > 0) ? (j % m) : 0;              // per-block rotation

    if (m > 0) {
        int s0 = (p + 2 * off) * 64;
        glds16(kg + (long)s0 * H_, kd0);  glds16(kg + (long)s0 * H_ + 8 * H_, kd0 + 8 * 64);
        glds16(vg + s0, vd0);             glds16(vg + s0 + 8 * T_, vd0 + 8 * 64);
    }

    for (int i = 0; i < m; ++i) {
        int cur = i & 1;
        __builtin_amdgcn_s_barrier();
        __builtin_amdgcn_sched_barrier(0);
        if (i + 1 < m) {
            int rot = i + 1 + off; if (rot >= m) rot -= m;
            int sn = (p + 2 * rot) * 64;
            unsigned short* kd = cur ? kd0 : kd1;
            unsigned short* vd = cur ? vd0 : vd1;
            glds16(kg + (long)sn * H_, kd);
            glds16(kg + (long)sn * H_ + 8 * H_, kd + 8 * 64);
            glds16(vg + sn, vd);
            glds16(vg + sn + 8 * T_, vd + 8 * 64);
            asm volatile("s_waitcnt vmcnt(4)" ::: "memory");
        } else {
            asm volatile("s_waitcnt vmcnt(0)" ::: "memory");
        }
        __builtin_amdgcn_sched_barrier(0);
        __builtin_amdgcn_s_barrier();
        __builtin_amdgcn_sched_barrier(0);

        int rotc = i + off; if (rotc >= m) rotc -= m;
        int s0 = (p + 2 * rotc) * 64;
        const unsigned short* kt = &kv[cur][0];
        const unsigned short* vtl = &kv[cur][4096];

        #pragma unroll
        for (int ct = 0; ct < 2; ++ct) {
            int row = sw * 32 + ct * 16 + l15;
            short8 k0 = *(const short8*)&kt[row * 64 + ((0 + lg) ^ (row & 7)) * 8];
            short8 k1 = *(const short8*)&kt[row * 64 + ((4 + lg) ^ (row & 7)) * 8];
            f32x4 acc = (f32x4){0.f, 0.f, 0.f, 0.f};
            acc = __builtin_amdgcn_mfma_f32_16x16x32_bf16(qa0, k0, acc, 0, 0, 0);
            acc = __builtin_amdgcn_mfma_f32_16x16x32_bf16(qa1, k1, acc, 0, 0, 0);
            int s = s0 + row;
            float rr = cR[s];
            #pragma unroll
            for (int r = 0; r < 4; ++r) {
                int t = t0 + qw * 16 + lg * 4 + r;
                float pv = __expf(acc[r] * SCALE) * rr;
                if (s > t) pv = 0.f;
                myp[(lg * 4 + r) * 40 + ct * 16 + l15] = f2bf(pv);
            }
        }
        short8 pa = *(const short8*)&myp[l15 * 40 + lg * 8];
        #pragma unroll
        for (int ht = 0; ht < 4; ++ht) {
            int vrow = ht * 16 + l15;
            short8 vf = *(const short8*)&vtl[vrow * 64 + ((sw * 4 + lg) ^ (vrow & 7)) * 8];
            o[ht] = __builtin_amdgcn_mfma_f32_16x16x32_bf16(pa, vf, o[ht], 0, 0, 0);
        }
    }

    __syncthreads();
    float* rbuf = (float*)&kv[0][0];               // [32 q][68] f32
    if (sw == 1) {
        #pragma unroll
        for (int ht = 0; ht < 4; ++ht)
            #pragma unroll
            for (int r = 0; r < 4; ++r)
                rbuf[(qw * 16 + lg * 4 + r) * 68 + ht * 16 + l15] = o[ht][r];
    }
    __syncthreads();
    if (sw == 0) {
        float* ob = out + ((long)b * T_ + t0 + qw * 16) * H_;
        #pragma unroll
        for (int ht = 0; ht < 4; ++ht)
            #pragma unroll
            for (int r = 0; r < 4; ++r) {
                int rr_ = lg * 4 + r, cc = ht * 16 + l15;
                unsafeAtomicAdd(&ob[(long)rr_ * H_ + cc],
                                o[ht][r] + rbuf[(qw * 16 + rr_) * 68 + cc]);
            }
    }
}

extern "C" void kernel_launch(void* const* d_in, const int* in_sizes, int n_in,
                              void* d_out, int out_size, void* d_ws, size_t ws_size,
                              hipStream_t stream) {
    const float* x  = (const float*)d_in[0];
    const float* Wk = (const float*)d_in[1];
    const float* Wq = (const float*)d_in[2];
    const float* Wv = (const float*)d_in[3];
    float* out = (float*)d_out;

    char* ws = (char*)d_ws;
    unsigned short* Wt = (unsigned short*)ws;                                  // 393216 B
    unsigned short* qb = (unsigned short*)(ws + 393216);                       // 2 MB
    unsigned short* kb = (unsigned short*)(ws + 393216 + 2097152);             // 2 MB
    unsigned short* vt = (unsigned short*)(ws + 393216 + 2 * 2097152);         // 2 MB
    float* colR = (float*)(ws + 393216 + 3 * 2097152);                         // 64 KB

    zero_prep<<<1072, 256, 0, stream>>>(out, Wq, Wk, Wv, Wt);
    qkv_gemm <<<512,  256, 0, stream>>>(x, Wt, qb, kb, vt);
    col_stats<<<1024, 256, 0, stream>>>(qb, kb, colR);
    attn_out <<<1024, 256, 0, stream>>>(qb, kb, vt, colR, out);
}

// Round 15
// 74.788 us; speedup vs baseline: 9.1077x; 1.0282x over previous
//
#include <hip/hip_runtime.h>
#include <hip/hip_bf16.h>

typedef __attribute__((ext_vector_type(8))) short short8;   // bf16x8 MFMA frag
typedef __attribute__((ext_vector_type(4))) float f32x4;    // fp32x4 acc

#define B_  8
#define T_  2048
#define E_  1024
#define H_  64
#define SCALE 0.03125f   // 1024^-0.5

__device__ inline unsigned short f2bf(float f) {
    unsigned int u = __builtin_bit_cast(unsigned int, f);
    unsigned int r = (u + 0x7FFFu + ((u >> 16) & 1u)) >> 16;   // RNE
    return (unsigned short)r;
}
__device__ inline unsigned int packbf(float lo, float hi) {
    return (unsigned int)f2bf(lo) | ((unsigned int)f2bf(hi) << 16);
}
__device__ inline void glds16(const void* g, void* l) {
    __builtin_amdgcn_global_load_lds((const __attribute__((address_space(1))) void*)g,
                                     (__attribute__((address_space(3))) void*)l, 16, 0, 0);
}

// ------------- kernel 0: W fp32 [1024][64] -> Wt bf16 [192][1024] (transposed) -------
__global__ __launch_bounds__(256) void prep_w(const float* __restrict__ Wq,
                                              const float* __restrict__ Wk,
                                              const float* __restrict__ Wv,
                                              unsigned short* __restrict__ Wt) {
    __shared__ float ls[64][65];
    int tid = threadIdx.x;
    int wsel = blockIdx.x >> 4, kt = blockIdx.x & 15;
    const float* W = (wsel == 0) ? Wq : (wsel == 1) ? Wk : Wv;
    int kr = tid >> 2, c4 = (tid & 3) * 16;
    const float* src = W + (long)(kt * 64 + kr) * H_ + c4;
    #pragma unroll
    for (int i = 0; i < 4; ++i) {
        float4 v = *(const float4*)(src + 4 * i);
        ls[kr][c4 + 4 * i + 0] = v.x; ls[kr][c4 + 4 * i + 1] = v.y;
        ls[kr][c4 + 4 * i + 2] = v.z; ls[kr][c4 + 4 * i + 3] = v.w;
    }
    __syncthreads();
    int c = tid >> 2, kk = (tid & 3) * 16;
    unsigned short* dst = Wt + (long)(wsel * 64 + c) * E_ + kt * 64 + kk;
    uint4 o1, o2;
    o1.x = packbf(ls[kk + 0][c], ls[kk + 1][c]);  o1.y = packbf(ls[kk + 2][c], ls[kk + 3][c]);
    o1.z = packbf(ls[kk + 4][c], ls[kk + 5][c]);  o1.w = packbf(ls[kk + 6][c], ls[kk + 7][c]);
    o2.x = packbf(ls[kk + 8][c], ls[kk + 9][c]);  o2.y = packbf(ls[kk + 10][c], ls[kk + 11][c]);
    o2.z = packbf(ls[kk + 12][c], ls[kk + 13][c]);o2.w = packbf(ls[kk + 14][c], ls[kk + 15][c]);
    *(uint4*)dst = o1;
    *(uint4*)(dst + 8) = o2;
}

// ---------------- kernel 1: QKV GEMM  [16384,1024] @ [1024,192] --------------------
// R7 structure rescaled to 512 threads: 8 waves = 2 row-halves x 4 col-quarters
// (3 acc tiles/wave). Rolling counted vmcnt(4) = this step's {1 x-load + 3 glds}
// stay in flight, prev step's 4 drained (N = new-op count => interleave-robust).
// 16 waves/CU (2 blocks x 8 waves) vs R7's 8.
__global__ __launch_bounds__(512, 4) void qkv_gemm(const float* __restrict__ x,
                                                   const unsigned short* __restrict__ Wt,
                                                   unsigned short* __restrict__ qb,
                                                   unsigned short* __restrict__ kb,
                                                   unsigned short* __restrict__ vt) {
    __shared__ unsigned short wlds[2][192 * 64];   // 49152 B, linear (glds dest)
    __shared__ unsigned short xlds[2][32 * 72];    // 9216 B, padded stride 144B

    int tid = threadIdx.x, lane = tid & 63, w = tid >> 6;   // 8 waves
    int l15 = lane & 15, lg = lane >> 4;
    int wr = w & 1, wc = w >> 1;                   // row half / col quarter
    int r0 = blockIdx.x * 32;
    int b = r0 >> 11, tb = r0 & 2047;

    // W staging: wave w stages Wt-rows 24w..24w+23 in 3 glds (8 rows x 8 chunks each);
    // LDS slot s8 holds global chunk s8^l8 = s8^(row&7)  (verified R7 scheme; 24w,8j = 0 mod 8)
    int l8 = lane >> 3, s8 = lane & 7;
    int swz = s8 ^ l8;
    const unsigned short* wg = Wt + (long)(24 * w + l8) * E_ + swz * 8;
    unsigned short* wl0 = &wlds[0][(24 * w) * 64];
    unsigned short* wl1 = &wlds[1][(24 * w) * 64];

    // x staging: thread -> row xr (32 rows), 4 floats at xcf
    int xr = tid >> 4, xcf = (tid & 15) * 4;
    const float* xg = x + (long)(r0 + xr) * E_ + xcf;

    f32x4 acc[3];
    #pragma unroll
    for (int i = 0; i < 3; ++i) acc[i] = (f32x4){0.f, 0.f, 0.f, 0.f};

    // prologue: stage k-step 0 into buf0
    {
        float4 xa = *(const float4*)xg;
        #pragma unroll
        for (int j = 0; j < 3; ++j)
            glds16(wg + (long)(8 * j) * E_, wl0 + (8 * j) * 64);
        uint2 ua; ua.x = packbf(xa.x, xa.y); ua.y = packbf(xa.z, xa.w);
        *(uint2*)&xlds[0][xr * 72 + xcf] = ua;
    }

    for (int ks = 0; ks < 16; ++ks) {
        int cur = ks & 1;
        __builtin_amdgcn_s_barrier();              // b1: all waves done with prev compute
        __builtin_amdgcn_sched_barrier(0);
        float4 xa;
        if (ks < 15) {
            int kp = (ks + 1) * 64;
            xa = *(const float4*)(xg + kp);        // 1 vmem
            unsigned short* wldst = cur ? wl0 : wl1;
            #pragma unroll
            for (int j = 0; j < 3; ++j)            // 3 vmem (glds)
                glds16(wg + (long)(8 * j) * E_ + kp, wldst + (8 * j) * 64);
            asm volatile("s_waitcnt vmcnt(4) lgkmcnt(0)" ::: "memory");
        } else {
            asm volatile("s_waitcnt vmcnt(0) lgkmcnt(0)" ::: "memory");
        }
        __builtin_amdgcn_sched_barrier(0);
        __builtin_amdgcn_s_barrier();              // b2: buf cur ready for everyone
        __builtin_amdgcn_sched_barrier(0);

        const char* wb = (const char*)&wlds[cur][0];
        const char* xsb = (const char*)&xlds[cur][0];
        #pragma unroll
        for (int kk2 = 0; kk2 < 2; ++kk2) {
            short8 a = *(const short8*)(xsb + (16 * wr + l15) * 144 + kk2 * 64 + lg * 16);
            #pragma unroll
            for (int ct = 0; ct < 3; ++ct) {
                int c = 48 * wc + 16 * ct + l15;
                int sp = (kk2 * 4 + lg) ^ (c & 7);
                short8 bf = *(const short8*)(wb + c * 128 + sp * 16);
                acc[ct] = __builtin_amdgcn_mfma_f32_16x16x32_bf16(a, bf, acc[ct], 0, 0, 0);
            }
        }
        if (ks < 15) {                             // x -> next buf (write after compute)
            uint2 ua; ua.x = packbf(xa.x, xa.y); ua.y = packbf(xa.z, xa.w);
            *(uint2*)&xlds[cur ^ 1][xr * 72 + xcf] = ua;
        }
    }

    // q/k epilogue: cols 0..127 direct
    #pragma unroll
    for (int ct = 0; ct < 3; ++ct) {
        int col = 48 * wc + 16 * ct + l15;
        if (col < 128) {
            unsigned short* dst = (col < 64) ? qb : kb;
            int n = col & 63;
            #pragma unroll
            for (int r = 0; r < 4; ++r) {
                int t = tb + 16 * wr + lg * 4 + r;
                dst[((long)b * T_ + t) * H_ + n] = f2bf(acc[ct][r]);
            }
        }
    }
    // v epilogue (cols 128..191) via LDS transpose in wlds[0] (disjoint from wlds[1]
    // still being read by step-15 compute of other waves)
    float* vbuf = (float*)&wlds[0][0];             // [32][68] fp32 = 8704B
    #pragma unroll
    for (int ct = 0; ct < 3; ++ct) {
        int col = 48 * wc + 16 * ct + l15;
        if (col >= 128) {
            int h = col - 128;
            #pragma unroll
            for (int r = 0; r < 4; ++r)
                vbuf[(16 * wr + lg * 4 + r) * 68 + h] = acc[ct][r];
        }
    }
    __syncthreads();
    {
        int h = tid >> 3, tc = (tid & 7) * 4;
        uint2 o;
        o.x = packbf(vbuf[(tc + 0) * 68 + h], vbuf[(tc + 1) * 68 + h]);
        o.y = packbf(vbuf[(tc + 2) * 68 + h], vbuf[(tc + 3) * 68 + h]);
        *(uint2*)&vt[((long)b * H_ + h) * T_ + tb + tc] = o;
    }
}

// ---------------- kernel 2: zero d_out + per-key-column sum of exp(score) -----------
// Zeroing folded in (1024 blocks x 256 thr x 16B = 4MB exact); stream order
// guarantees completion before attn_out's atomics.
__global__ __launch_bounds__(256) void col_stats(const unsigned short* __restrict__ qb,
                                                 const unsigned short* __restrict__ kb,
                                                 float* __restrict__ colR,
                                                 float* __restrict__ outz) {
    __shared__ float lD[4][16];
    int tid = threadIdx.x, lane = tid & 63, w = tid >> 6;
    {
        uint4 z = (uint4){0u, 0u, 0u, 0u};
        *(uint4*)(outz + ((long)blockIdx.x * 256 + tid) * 4) = z;
    }
    int b = blockIdx.x >> 7, c16 = blockIdx.x & 127;
    int sbase = c16 * 16;
    int l15 = lane & 15, lg = lane >> 4;

    const unsigned short* kp = kb + ((long)b * T_ + sbase + l15) * H_;
    short8 bk0 = *(const short8*)(kp + lg * 8);
    short8 bk1 = *(const short8*)(kp + 32 + lg * 8);

    float d1 = 0.f, d2 = 0.f;
    const unsigned short* qbase = qb + (long)b * T_ * H_;

    for (int t0 = sbase + 16 * w; t0 < T_; t0 += 128) {
        int t0b = t0 + 64;
        bool has2 = (t0b < T_);
        int t0c = has2 ? t0b : t0;
        const unsigned short* qp1 = qbase + (long)(t0 + l15) * H_ + lg * 8;
        const unsigned short* qp2 = qbase + (long)(t0c + l15) * H_ + lg * 8;
        short8 a0 = *(const short8*)qp1;
        short8 a1 = *(const short8*)(qp1 + 32);
        short8 c0 = *(const short8*)qp2;
        short8 c1 = *(const short8*)(qp2 + 32);

        f32x4 acc1 = (f32x4){0.f, 0.f, 0.f, 0.f};
        acc1 = __builtin_amdgcn_mfma_f32_16x16x32_bf16(a0, bk0, acc1, 0, 0, 0);
        acc1 = __builtin_amdgcn_mfma_f32_16x16x32_bf16(a1, bk1, acc1, 0, 0, 0);
        f32x4 acc2 = (f32x4){0.f, 0.f, 0.f, 0.f};
        acc2 = __builtin_amdgcn_mfma_f32_16x16x32_bf16(c0, bk0, acc2, 0, 0, 0);
        acc2 = __builtin_amdgcn_mfma_f32_16x16x32_bf16(c1, bk1, acc2, 0, 0, 0);

        #pragma unroll
        for (int r = 0; r < 4; ++r) {
            float e = __expf(acc1[r] * SCALE);
            if (t0 == sbase && (lg * 4 + r) < l15) e = 0.f;   // causal mask (diag tile)
            d1 += e;
        }
        if (has2) {
            #pragma unroll
            for (int r = 0; r < 4; ++r)
                d2 += __expf(acc2[r] * SCALE);
        }
    }
    float d = d1 + d2;
    d += __shfl_xor(d, 16, 64);
    d += __shfl_xor(d, 32, 64);
    if (lane < 16) lD[w][lane] = d;
    __syncthreads();
    if (tid < 16) {
        float df = lD[0][tid] + lD[1][tid] + lD[2][tid] + lD[3][tid];
        colR[b * T_ + sbase + tid] = 1.0f / df;
    }
}

// ---------------- kernel 3: out[t,h] = sum_{s<=t} exp(score)*R[s] * v[s,h] ----------
__global__ __launch_bounds__(256, 4) void attn_out(const unsigned short* __restrict__ qb,
                                                   const unsigned short* __restrict__ kb,
                                                   const unsigned short* __restrict__ vt,
                                                   const float* __restrict__ colR,
                                                   float* __restrict__ out) {
    __shared__ unsigned short kv[2][8192];        // [buf][ K 64x64 | V 64x64 ]  32 KB
    __shared__ unsigned short pbuf[4][16 * 40];   // per-wave P [16 q][32 s]      5 KB

    int tid = threadIdx.x, lane = tid & 63, w = tid >> 6;
    int qw = w & 1, sw = w >> 1;
    int l15 = lane & 15, lg = lane >> 4;
    int idx = blockIdx.x;
    int p = idx & 1;
    int b = (idx >> 1) & 7;
    int j = 63 - (idx >> 4);
    int t0 = j * 32;

    const unsigned short* kbase = kb + (long)b * T_ * H_;
    const unsigned short* vbase = vt + (long)b * H_ * T_;
    const float* cR = colR + b * T_;

    const unsigned short* qp = qb + ((long)b * T_ + t0 + qw * 16 + l15) * H_ + lg * 8;
    short8 qa0 = *(const short8*)qp;
    short8 qa1 = *(const short8*)(qp + 32);

    int l8 = lane >> 3, s8 = lane & 7;
    int swz8 = (s8 ^ l8) * 8;
    const unsigned short* kg = kbase + (long)(w * 16 + l8) * H_ + swz8;
    const unsigned short* vg = vbase + (long)(w * 16 + l8) * T_ + swz8;
    unsigned short* kd0 = &kv[0][w * 16 * 64];
    unsigned short* vd0 = &kv[0][4096 + w * 16 * 64];
    unsigned short* kd1 = &kv[1][w * 16 * 64];
    unsigned short* vd1 = &kv[1][4096 + w * 16 * 64];

    f32x4 o[4];
    #pragma unroll
    for (int i = 0; i < 4; ++i) o[i] = (f32x4){0.f, 0.f, 0.f, 0.f};
    unsigned short* myp = pbuf[w];

    int nstt = j / 2 + 1;
    int m = (nstt - p + 1) >> 1;                  // # of s-tiles for this block
    int off = (m > 0) ? (j % m) : 0;              // per-block rotation

    if (m > 0) {
        int s0 = (p + 2 * off) * 64;
        glds16(kg + (long)s0 * H_, kd0);  glds16(kg + (long)s0 * H_ + 8 * H_, kd0 + 8 * 64);
        glds16(vg + s0, vd0);             glds16(vg + s0 + 8 * T_, vd0 + 8 * 64);
    }

    for (int i = 0; i < m; ++i) {
        int cur = i & 1;
        __builtin_amdgcn_s_barrier();
        __builtin_amdgcn_sched_barrier(0);
        if (i + 1 < m) {
            int rot = i + 1 + off; if (rot >= m) rot -= m;
            int sn = (p + 2 * rot) * 64;
            unsigned short* kd = cur ? kd0 : kd1;
            unsigned short* vd = cur ? vd0 : vd1;
            glds16(kg + (long)sn * H_, kd);
            glds16(kg + (long)sn * H_ + 8 * H_, kd + 8 * 64);
            glds16(vg + sn, vd);
            glds16(vg + sn + 8 * T_, vd + 8 * 64);
            asm volatile("s_waitcnt vmcnt(4)" ::: "memory");
        } else {
            asm volatile("s_waitcnt vmcnt(0)" ::: "memory");
        }
        __builtin_amdgcn_sched_barrier(0);
        __builtin_amdgcn_s_barrier();
        __builtin_amdgcn_sched_barrier(0);

        int rotc = i + off; if (rotc >= m) rotc -= m;
        int s0 = (p + 2 * rotc) * 64;
        const unsigned short* kt = &kv[cur][0];
        const unsigned short* vtl = &kv[cur][4096];

        #pragma unroll
        for (int ct = 0; ct < 2; ++ct) {
            int row = sw * 32 + ct * 16 + l15;
            short8 k0 = *(const short8*)&kt[row * 64 + ((0 + lg) ^ (row & 7)) * 8];
            short8 k1 = *(const short8*)&kt[row * 64 + ((4 + lg) ^ (row & 7)) * 8];
            f32x4 acc = (f32x4){0.f, 0.f, 0.f, 0.f};
            acc = __builtin_amdgcn_mfma_f32_16x16x32_bf16(qa0, k0, acc, 0, 0, 0);
            acc = __builtin_amdgcn_mfma_f32_16x16x32_bf16(qa1, k1, acc, 0, 0, 0);
            int s = s0 + row;
            float rr = cR[s];
            #pragma unroll
            for (int r = 0; r < 4; ++r) {
                int t = t0 + qw * 16 + lg * 4 + r;
                float pv = __expf(acc[r] * SCALE) * rr;
                if (s > t) pv = 0.f;
                myp[(lg * 4 + r) * 40 + ct * 16 + l15] = f2bf(pv);
            }
        }
        short8 pa = *(const short8*)&myp[l15 * 40 + lg * 8];
        #pragma unroll
        for (int ht = 0; ht < 4; ++ht) {
            int vrow = ht * 16 + l15;
            short8 vf = *(const short8*)&vtl[vrow * 64 + ((sw * 4 + lg) ^ (vrow & 7)) * 8];
            o[ht] = __builtin_amdgcn_mfma_f32_16x16x32_bf16(pa, vf, o[ht], 0, 0, 0);
        }
    }

    __syncthreads();
    float* rbuf = (float*)&kv[0][0];               // [32 q][68] f32
    if (sw == 1) {
        #pragma unroll
        for (int ht = 0; ht < 4; ++ht)
            #pragma unroll
            for (int r = 0; r < 4; ++r)
                rbuf[(qw * 16 + lg * 4 + r) * 68 + ht * 16 + l15] = o[ht][r];
    }
    __syncthreads();
    if (sw == 0) {
        float* ob = out + ((long)b * T_ + t0 + qw * 16) * H_;
        #pragma unroll
        for (int ht = 0; ht < 4; ++ht)
            #pragma unroll
            for (int r = 0; r < 4; ++r) {
                int rr_ = lg * 4 + r, cc = ht * 16 + l15;
                unsafeAtomicAdd(&ob[(long)rr_ * H_ + cc],
                                o[ht][r] + rbuf[(qw * 16 + rr_) * 68 + cc]);
            }
    }
}

extern "C" void kernel_launch(void* const* d_in, const int* in_sizes, int n_in,
                              void* d_out, int out_size, void* d_ws, size_t ws_size,
                              hipStream_t stream) {
    const float* x  = (const float*)d_in[0];
    const float* Wk = (const float*)d_in[1];
    const float* Wq = (const float*)d_in[2];
    const float* Wv = (const float*)d_in[3];
    float* out = (float*)d_out;

    char* ws = (char*)d_ws;
    unsigned short* Wt = (unsigned short*)ws;                                  // 393216 B
    unsigned short* qb = (unsigned short*)(ws + 393216);                       // 2 MB
    unsigned short* kb = (unsigned short*)(ws + 393216 + 2097152);             // 2 MB
    unsigned short* vt = (unsigned short*)(ws + 393216 + 2 * 2097152);         // 2 MB
    float* colR = (float*)(ws + 393216 + 3 * 2097152);                         // 64 KB

    prep_w   <<<48,   256, 0, stream>>>(Wq, Wk, Wv, Wt);
    qkv_gemm <<<512,  512, 0, stream>>>(x, Wt, qb, kb, vt);
    col_stats<<<1024, 256, 0, stream>>>(qb, kb, colR, out);
    attn_out <<<1024, 256, 0, stream>>>(qb, kb, vt, colR, out);
}

// Round 17
// 74.468 us; speedup vs baseline: 9.1469x; 1.0043x over previous
//
#include <hip/hip_runtime.h>
#include <hip/hip_bf16.h>

typedef __attribute__((ext_vector_type(8))) short short8;   // bf16x8 MFMA frag
typedef __attribute__((ext_vector_type(4))) float f32x4;    // fp32x4 acc

#define B_  8
#define T_  2048
#define E_  1024
#define H_  64
#define SCALE 0.03125f   // 1024^-0.5

__device__ inline unsigned short f2bf(float f) {
    unsigned int u = __builtin_bit_cast(unsigned int, f);
    unsigned int r = (u + 0x7FFFu + ((u >> 16) & 1u)) >> 16;   // RNE
    return (unsigned short)r;
}
__device__ inline unsigned int packbf(float lo, float hi) {
    return (unsigned int)f2bf(lo) | ((unsigned int)f2bf(hi) << 16);
}
__device__ inline void glds16(const void* g, void* l) {
    __builtin_amdgcn_global_load_lds((const __attribute__((address_space(1))) void*)g,
                                     (__attribute__((address_space(3))) void*)l, 16, 0, 0);
}

// ------------- kernel 0: W fp32 [1024][64] -> Wt bf16 [192][1024] (transposed) -------
__global__ __launch_bounds__(256) void prep_w(const float* __restrict__ Wq,
                                              const float* __restrict__ Wk,
                                              const float* __restrict__ Wv,
                                              unsigned short* __restrict__ Wt) {
    __shared__ float ls[64][65];
    int tid = threadIdx.x;
    int wsel = blockIdx.x >> 4, kt = blockIdx.x & 15;
    const float* W = (wsel == 0) ? Wq : (wsel == 1) ? Wk : Wv;
    int kr = tid >> 2, c4 = (tid & 3) * 16;
    const float* src = W + (long)(kt * 64 + kr) * H_ + c4;
    #pragma unroll
    for (int i = 0; i < 4; ++i) {
        float4 v = *(const float4*)(src + 4 * i);
        ls[kr][c4 + 4 * i + 0] = v.x; ls[kr][c4 + 4 * i + 1] = v.y;
        ls[kr][c4 + 4 * i + 2] = v.z; ls[kr][c4 + 4 * i + 3] = v.w;
    }
    __syncthreads();
    int c = tid >> 2, kk = (tid & 3) * 16;
    unsigned short* dst = Wt + (long)(wsel * 64 + c) * E_ + kt * 64 + kk;
    uint4 o1, o2;
    o1.x = packbf(ls[kk + 0][c], ls[kk + 1][c]);  o1.y = packbf(ls[kk + 2][c], ls[kk + 3][c]);
    o1.z = packbf(ls[kk + 4][c], ls[kk + 5][c]);  o1.w = packbf(ls[kk + 6][c], ls[kk + 7][c]);
    o2.x = packbf(ls[kk + 8][c], ls[kk + 9][c]);  o2.y = packbf(ls[kk + 10][c], ls[kk + 11][c]);
    o2.z = packbf(ls[kk + 12][c], ls[kk + 13][c]);o2.w = packbf(ls[kk + 14][c], ls[kk + 15][c]);
    *(uint4*)dst = o1;
    *(uint4*)(dst + 8) = o2;
}

// ---------------- kernel 1: QKV GEMM  [16384,1024] @ [1024,192] --------------------
// R15 version (verified): 512 threads, 8 waves = 2 row-halves x 4 col-quarters,
// BK=64 W dbuf via glds, rolling counted vmcnt(4) (N = new-op count).
__global__ __launch_bounds__(512, 4) void qkv_gemm(const float* __restrict__ x,
                                                   const unsigned short* __restrict__ Wt,
                                                   unsigned short* __restrict__ qb,
                                                   unsigned short* __restrict__ kb,
                                                   unsigned short* __restrict__ vt) {
    __shared__ unsigned short wlds[2][192 * 64];   // 49152 B, linear (glds dest)
    __shared__ unsigned short xlds[2][32 * 72];    // 9216 B, padded stride 144B

    int tid = threadIdx.x, lane = tid & 63, w = tid >> 6;   // 8 waves
    int l15 = lane & 15, lg = lane >> 4;
    int wr = w & 1, wc = w >> 1;                   // row half / col quarter
    int r0 = blockIdx.x * 32;
    int b = r0 >> 11, tb = r0 & 2047;

    int l8 = lane >> 3, s8 = lane & 7;
    int swz = s8 ^ l8;
    const unsigned short* wg = Wt + (long)(24 * w + l8) * E_ + swz * 8;
    unsigned short* wl0 = &wlds[0][(24 * w) * 64];
    unsigned short* wl1 = &wlds[1][(24 * w) * 64];

    int xr = tid >> 4, xcf = (tid & 15) * 4;
    const float* xg = x + (long)(r0 + xr) * E_ + xcf;

    f32x4 acc[3];
    #pragma unroll
    for (int i = 0; i < 3; ++i) acc[i] = (f32x4){0.f, 0.f, 0.f, 0.f};

    {
        float4 xa = *(const float4*)xg;
        #pragma unroll
        for (int j = 0; j < 3; ++j)
            glds16(wg + (long)(8 * j) * E_, wl0 + (8 * j) * 64);
        uint2 ua; ua.x = packbf(xa.x, xa.y); ua.y = packbf(xa.z, xa.w);
        *(uint2*)&xlds[0][xr * 72 + xcf] = ua;
    }

    for (int ks = 0; ks < 16; ++ks) {
        int cur = ks & 1;
        __builtin_amdgcn_s_barrier();              // b1: all waves done with prev compute
        __builtin_amdgcn_sched_barrier(0);
        float4 xa;
        if (ks < 15) {
            int kp = (ks + 1) * 64;
            xa = *(const float4*)(xg + kp);        // 1 vmem
            unsigned short* wldst = cur ? wl0 : wl1;
            #pragma unroll
            for (int j = 0; j < 3; ++j)            // 3 vmem (glds)
                glds16(wg + (long)(8 * j) * E_ + kp, wldst + (8 * j) * 64);
            asm volatile("s_waitcnt vmcnt(4) lgkmcnt(0)" ::: "memory");
        } else {
            asm volatile("s_waitcnt vmcnt(0) lgkmcnt(0)" ::: "memory");
        }
        __builtin_amdgcn_sched_barrier(0);
        __builtin_amdgcn_s_barrier();              // b2: buf cur ready for everyone
        __builtin_amdgcn_sched_barrier(0);

        const char* wb = (const char*)&wlds[cur][0];
        const char* xsb = (const char*)&xlds[cur][0];
        #pragma unroll
        for (int kk2 = 0; kk2 < 2; ++kk2) {
            short8 a = *(const short8*)(xsb + (16 * wr + l15) * 144 + kk2 * 64 + lg * 16);
            #pragma unroll
            for (int ct = 0; ct < 3; ++ct) {
                int c = 48 * wc + 16 * ct + l15;
                int sp = (kk2 * 4 + lg) ^ (c & 7);
                short8 bf = *(const short8*)(wb + c * 128 + sp * 16);
                acc[ct] = __builtin_amdgcn_mfma_f32_16x16x32_bf16(a, bf, acc[ct], 0, 0, 0);
            }
        }
        if (ks < 15) {
            uint2 ua; ua.x = packbf(xa.x, xa.y); ua.y = packbf(xa.z, xa.w);
            *(uint2*)&xlds[cur ^ 1][xr * 72 + xcf] = ua;
        }
    }

    #pragma unroll
    for (int ct = 0; ct < 3; ++ct) {
        int col = 48 * wc + 16 * ct + l15;
        if (col < 128) {
            unsigned short* dst = (col < 64) ? qb : kb;
            int n = col & 63;
            #pragma unroll
            for (int r = 0; r < 4; ++r) {
                int t = tb + 16 * wr + lg * 4 + r;
                dst[((long)b * T_ + t) * H_ + n] = f2bf(acc[ct][r]);
            }
        }
    }
    float* vbuf = (float*)&wlds[0][0];             // [32][68] fp32 = 8704B
    #pragma unroll
    for (int ct = 0; ct < 3; ++ct) {
        int col = 48 * wc + 16 * ct + l15;
        if (col >= 128) {
            int h = col - 128;
            #pragma unroll
            for (int r = 0; r < 4; ++r)
                vbuf[(16 * wr + lg * 4 + r) * 68 + h] = acc[ct][r];
        }
    }
    __syncthreads();
    {
        int h = tid >> 3, tc = (tid & 7) * 4;
        uint2 o;
        o.x = packbf(vbuf[(tc + 0) * 68 + h], vbuf[(tc + 1) * 68 + h]);
        o.y = packbf(vbuf[(tc + 2) * 68 + h], vbuf[(tc + 3) * 68 + h]);
        *(uint2*)&vt[((long)b * H_ + h) * T_ + tb + tc] = o;
    }
}

// ---------------- kernel 2: zero d_out + per-key-column sum of exp(score) -----------
// v3: FOUR independent (load->MFMA->exp->add) chains per wave (stride 256) — 2x the
// memory-level parallelism of R15's two-chain version; mask confined to chain0's
// first tile (chains 1-3 start >= sbase+64 > diagonal).
__global__ __launch_bounds__(256) void col_stats(const unsigned short* __restrict__ qb,
                                                 const unsigned short* __restrict__ kb,
                                                 float* __restrict__ colR,
                                                 float* __restrict__ outz) {
    __shared__ float lD[4][16];
    int tid = threadIdx.x, lane = tid & 63, w = tid >> 6;
    {
        uint4 z = (uint4){0u, 0u, 0u, 0u};
        *(uint4*)(outz + ((long)blockIdx.x * 256 + tid) * 4) = z;
    }
    int b = blockIdx.x >> 7, c16 = blockIdx.x & 127;
    int sbase = c16 * 16;
    int l15 = lane & 15, lg = lane >> 4;

    const unsigned short* kp = kb + ((long)b * T_ + sbase + l15) * H_;
    short8 bk0 = *(const short8*)(kp + lg * 8);
    short8 bk1 = *(const short8*)(kp + 32 + lg * 8);

    float d0 = 0.f, d1 = 0.f, d2 = 0.f, d3 = 0.f;
    const unsigned short* qbase = qb + (long)b * T_ * H_;

    for (int t0 = sbase + 16 * w; t0 < T_; t0 += 256) {
        int t1 = t0 + 64, t2 = t0 + 128, t3 = t0 + 192;
        bool h1 = (t1 < T_), h2 = (t2 < T_), h3 = (t3 < T_);
        int t1c = h1 ? t1 : t0, t2c = h2 ? t2 : t0, t3c = h3 ? t3 : t0;
        const unsigned short* qp0 = qbase + (long)(t0 + l15) * H_ + lg * 8;
        const unsigned short* qp1 = qbase + (long)(t1c + l15) * H_ + lg * 8;
        const unsigned short* qp2 = qbase + (long)(t2c + l15) * H_ + lg * 8;
        const unsigned short* qp3 = qbase + (long)(t3c + l15) * H_ + lg * 8;
        short8 a00 = *(const short8*)qp0, a01 = *(const short8*)(qp0 + 32);
        short8 a10 = *(const short8*)qp1, a11 = *(const short8*)(qp1 + 32);
        short8 a20 = *(const short8*)qp2, a21 = *(const short8*)(qp2 + 32);
        short8 a30 = *(const short8*)qp3, a31 = *(const short8*)(qp3 + 32);

        f32x4 x0 = (f32x4){0.f, 0.f, 0.f, 0.f};
        x0 = __builtin_amdgcn_mfma_f32_16x16x32_bf16(a00, bk0, x0, 0, 0, 0);
        x0 = __builtin_amdgcn_mfma_f32_16x16x32_bf16(a01, bk1, x0, 0, 0, 0);
        f32x4 x1 = (f32x4){0.f, 0.f, 0.f, 0.f};
        x1 = __builtin_amdgcn_mfma_f32_16x16x32_bf16(a10, bk0, x1, 0, 0, 0);
        x1 = __builtin_amdgcn_mfma_f32_16x16x32_bf16(a11, bk1, x1, 0, 0, 0);
        f32x4 x2 = (f32x4){0.f, 0.f, 0.f, 0.f};
        x2 = __builtin_amdgcn_mfma_f32_16x16x32_bf16(a20, bk0, x2, 0, 0, 0);
        x2 = __builtin_amdgcn_mfma_f32_16x16x32_bf16(a21, bk1, x2, 0, 0, 0);
        f32x4 x3 = (f32x4){0.f, 0.f, 0.f, 0.f};
        x3 = __builtin_amdgcn_mfma_f32_16x16x32_bf16(a30, bk0, x3, 0, 0, 0);
        x3 = __builtin_amdgcn_mfma_f32_16x16x32_bf16(a31, bk1, x3, 0, 0, 0);

        #pragma unroll
        for (int r = 0; r < 4; ++r) {
            float e = __expf(x0[r] * SCALE);
            if (t0 == sbase && (lg * 4 + r) < l15) e = 0.f;   // causal mask (diag tile)
            d0 += e;
        }
        if (h1) {
            for (int r = 0; r < 4; ++r) d1 += __expf(x1[r] * SCALE);
        }
        if (h2) {
            for (int r = 0; r < 4; ++r) d2 += __expf(x2[r] * SCALE);
        }
        if (h3) {
            for (int r = 0; r < 4; ++r) d3 += __expf(x3[r] * SCALE);
        }
    }
    float d = (d0 + d1) + (d2 + d3);
    d += __shfl_xor(d, 16, 64);
    d += __shfl_xor(d, 32, 64);
    if (lane < 16) lD[w][lane] = d;
    __syncthreads();
    if (tid < 16) {
        float df = lD[0][tid] + lD[1][tid] + lD[2][tid] + lD[3][tid];
        colR[b * T_ + sbase + tid] = 1.0f / df;
    }
}

// ---------------- kernel 3: out[t,h] = sum_{s<=t} exp(score)*R[s] * v[s,h] ----------
__global__ __launch_bounds__(256, 4) void attn_out(const unsigned short* __restrict__ qb,
                                                   const unsigned short* __restrict__ kb,
                                                   const unsigned short* __restrict__ vt,
                                                   const float* __restrict__ colR,
                                                   float* __restrict__ out) {
    __shared__ unsigned short kv[2][8192];        // [buf][ K 64x64 | V 64x64 ]  32 KB
    __shared__ unsigned short pbuf[4][16 * 40];   // per-wave P [16 q][32 s]      5 KB

    int tid = threadIdx.x, lane = tid & 63, w = tid >> 6;
    int qw = w & 1, sw = w >> 1;
    int l15 = lane & 15, lg = lane >> 4;
    int idx = blockIdx.x;
    int p = idx & 1;
    int b = (idx >> 1) & 7;
    int j = 63 - (idx >> 4);
    int t0 = j * 32;

    const unsigned short* kbase = kb + (long)b * T_ * H_;
    const unsigned short* vbase = vt + (long)b * H_ * T_;
    const float* cR = colR + b * T_;

    const unsigned short* qp = qb + ((long)b * T_ + t0 + qw * 16 + l15) * H_ + lg * 8;
    short8 qa0 = *(const short8*)qp;
    short8 qa1 = *(const short8*)(qp + 32);

    int l8 = lane >> 3, s8 = lane & 7;
    int swz8 = (s8 ^ l8) * 8;
    const unsigned short* kg = kbase + (long)(w * 16 + l8) * H_ + swz8;
    const unsigned short* vg = vbase + (long)(w * 16 + l8) * T_ + swz8;
    unsigned short* kd0 = &kv[0][w * 16 * 64];
    unsigned short* vd0 = &kv[0][4096 + w * 16 * 64];
    unsigned short* kd1 = &kv[1][w * 16 * 64];
    unsigned short* vd1 = &kv[1][4096 + w * 16 * 64];

    f32x4 o[4];
    #pragma unroll
    for (int i = 0; i < 4; ++i) o[i] = (f32x4){0.f, 0.f, 0.f, 0.f};
    unsigned short* myp = pbuf[w];

    int nstt = j / 2 + 1;
    int m = (nstt - p + 1) >> 1;                  // # of s-tiles for this block
    int off = (m > 0) ? (j % m) : 0;              // per-block rotation

    if (m > 0) {
        int s0 = (p + 2 * off) * 64;
        glds16(kg + (long)s0 * H_, kd0);  glds16(kg + (long)s0 * H_ + 8 * H_, kd0 + 8 * 64);
        glds16(vg + s0, vd0);             glds16(vg + s0 + 8 * T_, vd0 + 8 * 64);
    }

    for (int i = 0; i < m; ++i) {
        int cur = i & 1;
        __builtin_amdgcn_s_barrier();
        __builtin_amdgcn_sched_barrier(0);
        if (i + 1 < m) {
            int rot = i + 1 + off; if (rot >= m) rot -= m;
            int sn = (p + 2 * rot) * 64;
            unsigned short* kd = cur ? kd0 : kd1;
            unsigned short* vd = cur ? vd0 : vd1;
            glds16(kg + (long)sn * H_, kd);
            glds16(kg + (long)sn * H_ + 8 * H_, kd + 8 * 64);
            glds16(vg + sn, vd);
            glds16(vg + sn + 8 * T_, vd + 8 * 64);
            asm volatile("s_waitcnt vmcnt(4)" ::: "memory");
        } else {
            asm volatile("s_waitcnt vmcnt(0)" ::: "memory");
        }
        __builtin_amdgcn_sched_barrier(0);
        __builtin_amdgcn_s_barrier();
        __builtin_amdgcn_sched_barrier(0);

        int rotc = i + off; if (rotc >= m) rotc -= m;
        int s0 = (p + 2 * rotc) * 64;
        const unsigned short* kt = &kv[cur][0];
        const unsigned short* vtl = &kv[cur][4096];

        #pragma unroll
        for (int ct = 0; ct < 2; ++ct) {
            int row = sw * 32 + ct * 16 + l15;
            short8 k0 = *(const short8*)&kt[row * 64 + ((0 + lg) ^ (row & 7)) * 8];
            short8 k1 = *(const short8*)&kt[row * 64 + ((4 + lg) ^ (row & 7)) * 8];
            f32x4 acc = (f32x4){0.f, 0.f, 0.f, 0.f};
            acc = __builtin_amdgcn_mfma_f32_16x16x32_bf16(qa0, k0, acc, 0, 0, 0);
            acc = __builtin_amdgcn_mfma_f32_16x16x32_bf16(qa1, k1, acc, 0, 0, 0);
            int s = s0 + row;
            float rr = cR[s];
            #pragma unroll
            for (int r = 0; r < 4; ++r) {
                int t = t0 + qw * 16 + lg * 4 + r;
                float pv = __expf(acc[r] * SCALE) * rr;
                if (s > t) pv = 0.f;
                myp[(lg * 4 + r) * 40 + ct * 16 + l15] = f2bf(pv);
            }
        }
        short8 pa = *(const short8*)&myp[l15 * 40 + lg * 8];
        #pragma unroll
        for (int ht = 0; ht < 4; ++ht) {
            int vrow = ht * 16 + l15;
            short8 vf = *(const short8*)&vtl[vrow * 64 + ((sw * 4 + lg) ^ (vrow & 7)) * 8];
            o[ht] = __builtin_amdgcn_mfma_f32_16x16x32_bf16(pa, vf, o[ht], 0, 0, 0);
        }
    }

    __syncthreads();
    float* rbuf = (float*)&kv[0][0];               // [32 q][68] f32
    if (sw == 1) {
        #pragma unroll
        for (int ht = 0; ht < 4; ++ht)
            #pragma unroll
            for (int r = 0; r < 4; ++r)
                rbuf[(qw * 16 + lg * 4 + r) * 68 + ht * 16 + l15] = o[ht][r];
    }
    __syncthreads();
    if (sw == 0) {
        float* ob = out + ((long)b * T_ + t0 + qw * 16) * H_;
        #pragma unroll
        for (int ht = 0; ht < 4; ++ht)
            #pragma unroll
            for (int r = 0; r < 4; ++r) {
                int rr_ = lg * 4 + r, cc = ht * 16 + l15;
                unsafeAtomicAdd(&ob[(long)rr_ * H_ + cc],
                                o[ht][r] + rbuf[(qw * 16 + rr_) * 68 + cc]);
            }
    }
}

extern "C" void kernel_launch(void* const* d_in, const int* in_sizes, int n_in,
                              void* d_out, int out_size, void* d_ws, size_t ws_size,
                              hipStream_t stream) {
    const float* x  = (const float*)d_in[0];
    const float* Wk = (const float*)d_in[1];
    const float* Wq = (const float*)d_in[2];
    const float* Wv = (const float*)d_in[3];
    float* out = (float*)d_out;

    char* ws = (char*)d_ws;
    unsigned short* Wt = (unsigned short*)ws;                                  // 393216 B
    unsigned short* qb = (unsigned short*)(ws + 393216);                       // 2 MB
    unsigned short* kb = (unsigned short*)(ws + 393216 + 2097152);             // 2 MB
    unsigned short* vt = (unsigned short*)(ws + 393216 + 2 * 2097152);         // 2 MB
    float* colR = (float*)(ws + 393216 + 3 * 2097152);                         // 64 KB

    prep_w   <<<48,   256, 0, stream>>>(Wq, Wk, Wv, Wt);
    qkv_gemm <<<512,  512, 0, stream>>>(x, Wt, qb, kb, vt);
    col_stats<<<1024, 256, 0, stream>>>(qb, kb, colR, out);
    attn_out <<<1024, 256, 0, stream>>>(qb, kb, vt, colR, out);
}